// Round 1
// baseline (327.518 us; speedup 1.0000x reference)
//
#include <hip/hip_runtime.h>
#include <cstdint>
#include <cstddef>

#define NTOK 8192
#define NEXP 8
#define CAP 1280
#define CDIM 768
#define IDIM 3072
#define EROWS (NEXP*CAP)   /* 10240 */

typedef __attribute__((ext_vector_type(8))) short short8;
typedef __attribute__((ext_vector_type(4))) float f32x4;
typedef __attribute__((ext_vector_type(4))) unsigned short us4;

__device__ __forceinline__ unsigned short f2b(float f) {
  unsigned u = __builtin_bit_cast(unsigned, f);
  u += 0x7FFFu + ((u >> 16) & 1u);          // round-to-nearest-even
  return (unsigned short)(u >> 16);
}

// ---------------- weight transpose + f32->bf16 convert ----------------
// src: [E][R][S] f32  ->  dst: [E][S][R] bf16
__global__ __launch_bounds__(256) void transpose_cvt(const float* __restrict__ src,
    unsigned short* __restrict__ dst, int R, int S) {
  int tilesS = S >> 5, tilesR = R >> 5;
  int perE = tilesR * tilesS;
  int e = blockIdx.x / perE;
  int rem = blockIdx.x % perE;
  int rt = rem / tilesS, st = rem % tilesS;
  const float* se = src + (size_t)e*R*S + ((size_t)rt*32)*S + st*32;
  unsigned short* de = dst + (size_t)e*R*S + ((size_t)st*32)*R + rt*32;
  __shared__ float tile[32][33];
  int tx = threadIdx.x & 31, ty = threadIdx.x >> 5;   // ty 0..7
#pragma unroll
  for (int k = 0; k < 4; ++k) tile[ty + 8*k][tx] = se[(size_t)(ty + 8*k)*S + tx];
  __syncthreads();
#pragma unroll
  for (int k = 0; k < 4; ++k) de[(size_t)(ty + 8*k)*R + tx] = f2b(tile[tx][ty + 8*k]);
}

// ---------------- router: logits, softmax, top-2, raw gates ----------------
__global__ __launch_bounds__(256) void router_kernel(const float* __restrict__ x,
    const float* __restrict__ Wr, float* __restrict__ probs,
    int* __restrict__ idx1, int* __restrict__ idx2,
    float* __restrict__ g1r, float* __restrict__ g2r) {
  __shared__ float WrT[NEXP*CDIM];
  for (int i = threadIdx.x; i < NEXP*CDIM; i += 256) {
    int c = i >> 3, e = i & 7;
    WrT[e*CDIM + c] = Wr[i];
  }
  __syncthreads();
  int w = threadIdx.x >> 6, l = threadIdx.x & 63;
  int t = blockIdx.x*4 + w;
  float acc[NEXP];
#pragma unroll
  for (int e = 0; e < NEXP; ++e) acc[e] = 0.f;
  for (int k = 0; k < CDIM/64; ++k) {
    float xv = x[(size_t)t*CDIM + k*64 + l];
#pragma unroll
    for (int e = 0; e < NEXP; ++e) acc[e] += xv * WrT[e*CDIM + k*64 + l];
  }
#pragma unroll
  for (int off = 32; off > 0; off >>= 1) {
#pragma unroll
    for (int e = 0; e < NEXP; ++e) acc[e] += __shfl_xor(acc[e], off);
  }
  if (l == 0) {
    float m = acc[0];
#pragma unroll
    for (int e = 1; e < NEXP; ++e) m = fmaxf(m, acc[e]);
    float p[NEXP]; float s = 0.f;
#pragma unroll
    for (int e = 0; e < NEXP; ++e) { p[e] = expf(acc[e] - m); s += p[e]; }
    float inv = 1.f / s;
#pragma unroll
    for (int e = 0; e < NEXP; ++e) { p[e] *= inv; probs[(size_t)t*NEXP + e] = p[e]; }
    int i1 = 0; float b1 = p[0];
#pragma unroll
    for (int e = 1; e < NEXP; ++e) if (p[e] > b1) { b1 = p[e]; i1 = e; }
    int i2 = -1; float b2 = -1e30f;
#pragma unroll
    for (int e = 0; e < NEXP; ++e) if (e != i1 && p[e] > b2) { b2 = p[e]; i2 = e; }
    float gs = fmaxf(b1 + b2, 1e-9f);
    g1r[t] = b1 / gs; g2r[t] = b2 / gs;
    idx1[t] = i1; idx2[t] = i2;
  }
}

// ---------------- scan: capacity positions, bufmap, gates, aux ----------------
__global__ __launch_bounds__(1024) void scan_kernel(
    const int* __restrict__ idx1, const int* __restrict__ idx2,
    const float* __restrict__ g1r, const float* __restrict__ g2r,
    const float* __restrict__ probs,
    int* __restrict__ bufmap,          // pre-memset to -1
    int* __restrict__ c1o, int* __restrict__ c2o,
    float* __restrict__ g1o, float* __restrict__ g2o,
    float* __restrict__ aux_out) {
  __shared__ unsigned int scanbuf[1024][9];
  __shared__ unsigned int totals[NEXP];
  int tid = threadIdx.x;
  int e1[8], e2[8];
  unsigned int cnt[NEXP];
#pragma unroll
  for (int k = 0; k < NEXP; ++k) cnt[k] = 0;
  for (int j = 0; j < 8; ++j) {
    int t = tid*8 + j;
    e1[j] = idx1[t]; e2[j] = idx2[t];
    cnt[e1[j]] += 1u;            // low 16: first-choice count
    cnt[e2[j]] += (1u << 16);    // high 16: second-choice count
  }
#pragma unroll
  for (int k = 0; k < NEXP; ++k) scanbuf[tid][k] = cnt[k];
  unsigned int run[NEXP];
#pragma unroll
  for (int k = 0; k < NEXP; ++k) run[k] = cnt[k];
  __syncthreads();
  for (int off = 1; off < 1024; off <<= 1) {
    unsigned int add[NEXP];
#pragma unroll
    for (int k = 0; k < NEXP; ++k) add[k] = 0;
    if (tid >= off) {
#pragma unroll
      for (int k = 0; k < NEXP; ++k) add[k] = scanbuf[tid - off][k];
    }
    __syncthreads();
#pragma unroll
    for (int k = 0; k < NEXP; ++k) { run[k] += add[k]; scanbuf[tid][k] = run[k]; }
    __syncthreads();
  }
  if (tid == 1023) {
#pragma unroll
    for (int k = 0; k < NEXP; ++k) totals[k] = run[k];
  }
  __syncthreads();
  unsigned int excl[NEXP];
#pragma unroll
  for (int k = 0; k < NEXP; ++k) excl[k] = run[k] - cnt[k];
  int cnt1c[NEXP];
#pragma unroll
  for (int k = 0; k < NEXP; ++k) cnt1c[k] = min((int)(totals[k] & 0xFFFFu), CAP);

  for (int j = 0; j < 8; ++j) {
    int t = tid*8 + j;
    int a = e1[j];
    int pos1 = (int)(excl[a] & 0xFFFFu); excl[a] += 1u;
    int slot1 = a*CAP + pos1;
    bool m1 = pos1 < CAP;
    if (m1) bufmap[slot1] = t;
    int b = e2[j];
    int pos2 = (int)(excl[b] >> 16) + cnt1c[b]; excl[b] += (1u << 16);
    int slot2 = b*CAP + pos2;
    bool m2 = pos2 < CAP;
    if (m2) bufmap[slot2] = t;
    float G1 = m1 ? g1r[t] : 0.f;
    float G2 = m2 ? g2r[t] : 0.f;
    float den = fmaxf(G1 + G2, 1e-9f);
    g1o[t] = G1 / den; g2o[t] = G2 / den;
    c1o[t] = min(slot1, EROWS - 1);
    c2o[t] = min(slot2, EROWS - 1);
  }

  // deterministic importance reduction
  float imp[NEXP];
#pragma unroll
  for (int k = 0; k < NEXP; ++k) imp[k] = 0.f;
  for (int j = 0; j < 8; ++j) {
    int t = tid*8 + j;
    const float4* pr = (const float4*)(probs + (size_t)t*NEXP);
    float4 a0 = pr[0], a1 = pr[1];
    imp[0] += a0.x; imp[1] += a0.y; imp[2] += a0.z; imp[3] += a0.w;
    imp[4] += a1.x; imp[5] += a1.y; imp[6] += a1.z; imp[7] += a1.w;
  }
  __syncthreads();
  float* fbuf = (float*)&scanbuf[0][0];
#pragma unroll
  for (int k = 0; k < NEXP; ++k) fbuf[tid*9 + k] = imp[k];
  __syncthreads();
  for (int s = 512; s >= 1; s >>= 1) {
    if (tid < s) {
#pragma unroll
      for (int k = 0; k < NEXP; ++k) fbuf[tid*9 + k] += fbuf[(tid + s)*9 + k];
    }
    __syncthreads();
  }
  if (tid == 0) {
    float aux = 0.f;
#pragma unroll
    for (int k = 0; k < NEXP; ++k) {
      float importance = fbuf[k] / (float)NTOK;
      float loadk = (float)((totals[k] & 0xFFFFu) + (totals[k] >> 16)) / ((float)NTOK * 2.0f);
      aux += importance * loadk;
    }
    aux_out[0] = aux * (float)NEXP * 0.01f;
  }
}

// ---------------- dispatch: gather x -> ein (bf16) ----------------
__global__ __launch_bounds__(192) void dispatch_kernel(const float* __restrict__ x,
    const int* __restrict__ bufmap, unsigned short* __restrict__ ein) {
  int r = blockIdx.x;
  int t = bufmap[r];
  int q = threadIdx.x;   // 0..191, 4 floats each
  float4 v = make_float4(0.f, 0.f, 0.f, 0.f);
  if (t >= 0) v = ((const float4*)x)[(size_t)t*(CDIM/4) + q];
  us4 o;
  o.x = f2b(v.x); o.y = f2b(v.y); o.z = f2b(v.z); o.w = f2b(v.w);
  ((us4*)ein)[(size_t)r*(CDIM/4) + q] = o;
}

// ---------------- m97-style bf16 MFMA GEMM (A[M,K] x B^T[N,K]) ----------------
// DUAL: two B operands, epilogue h = silu(A*B0) * (A*B1) -> bf16
// else: f32 output.
template<int K, bool DUAL, bool NOUTER>
__global__ __launch_bounds__(256, 2) void gemm_bt(
    const unsigned short* __restrict__ A,
    const unsigned short* __restrict__ B0,
    const unsigned short* __restrict__ B1,
    unsigned short* __restrict__ Hout,
    float* __restrict__ Fout,
    int Ntiles, int N) {
  constexpr int MT = 10;                       // 1280/128 per expert
  int chunk = gridDim.x >> 3;                  // grid % 8 == 0 (bijective XCD swizzle)
  int bid = blockIdx.x;
  int tile = (bid & 7)*chunk + (bid >> 3);
  int perE = MT * Ntiles;
  int e = tile / perE, rem = tile % perE;
  int mt, nt;
  if (NOUTER) { nt = rem / MT; mt = rem % MT; }
  else        { mt = rem / Ntiles; nt = rem % Ntiles; }

  const unsigned short* Ae  = A  + (size_t)e*CAP*K + (size_t)mt*128*K;
  const unsigned short* B0e = B0 + (size_t)e*N*K   + (size_t)nt*128*K;
  const unsigned short* B1e = nullptr;
  if constexpr (DUAL) B1e = B1 + (size_t)e*N*K + (size_t)nt*128*K;

  __shared__ unsigned short Alds[128*64];
  __shared__ unsigned short B0lds[128*64];
  __shared__ unsigned short B1lds[DUAL ? 128*64 : 8];

  int tid = threadIdx.x;
  int l = tid & 63, w = tid >> 6;
  int rbase = w*8 + (l >> 3);                  // staging row (q adds 32)
  int csrc  = (l & 7) ^ ((l >> 3) & 7);        // pre-swizzled source k-chunk
  size_t gbase = (size_t)rbase*K + (size_t)csrc*8;
  int ldsoff = w*512;                          // ushort units; +q*2048

  f32x4 acc0[16];
  f32x4 acc1[DUAL ? 16 : 1];
#pragma unroll
  for (int i = 0; i < 16; ++i) acc0[i] = (f32x4){0.f,0.f,0.f,0.f};
  if constexpr (DUAL) {
#pragma unroll
    for (int i = 0; i < 16; ++i) acc1[i] = (f32x4){0.f,0.f,0.f,0.f};
  }

  int wm = (w >> 1)*64, wn = (w & 1)*64;
  int lrow = l & 15, khi = l >> 4;

  for (int kt = 0; kt < K/64; ++kt) {
    const unsigned short* Ag  = Ae  + gbase + (size_t)kt*64;
    const unsigned short* Bg0 = B0e + gbase + (size_t)kt*64;
#pragma unroll
    for (int q = 0; q < 4; ++q) {
      __builtin_amdgcn_global_load_lds(
          (const __attribute__((address_space(1))) void*)(Ag + (size_t)q*32*K),
          (__attribute__((address_space(3))) void*)(Alds + ldsoff + q*2048), 16, 0, 0);
    }
#pragma unroll
    for (int q = 0; q < 4; ++q) {
      __builtin_amdgcn_global_load_lds(
          (const __attribute__((address_space(1))) void*)(Bg0 + (size_t)q*32*K),
          (__attribute__((address_space(3))) void*)(B0lds + ldsoff + q*2048), 16, 0, 0);
    }
    if constexpr (DUAL) {
      const unsigned short* Bg1 = B1e + gbase + (size_t)kt*64;
#pragma unroll
      for (int q = 0; q < 4; ++q) {
        __builtin_amdgcn_global_load_lds(
            (const __attribute__((address_space(1))) void*)(Bg1 + (size_t)q*32*K),
            (__attribute__((address_space(3))) void*)(B1lds + ldsoff + q*2048), 16, 0, 0);
      }
    }
    __syncthreads();
#pragma unroll
    for (int kk = 0; kk < 2; ++kk) {
      int cs = (kk*4 + khi) ^ (l & 7);         // swizzled 16B slot (row&7 == l&7 for all frags)
      short8 af[4];
#pragma unroll
      for (int m = 0; m < 4; ++m) {
        int row = wm + m*16 + lrow;
        af[m] = *(const short8*)(Alds + row*64 + cs*8);
      }
#pragma unroll
      for (int n = 0; n < 4; ++n) {
        int rowb = wn + n*16 + lrow;
        short8 b0 = *(const short8*)(B0lds + rowb*64 + cs*8);
#pragma unroll
        for (int m = 0; m < 4; ++m)
          acc0[m*4+n] = __builtin_amdgcn_mfma_f32_16x16x32_bf16(af[m], b0, acc0[m*4+n], 0, 0, 0);
        if constexpr (DUAL) {
          short8 b1 = *(const short8*)(B1lds + rowb*64 + cs*8);
#pragma unroll
          for (int m = 0; m < 4; ++m)
            acc1[m*4+n] = __builtin_amdgcn_mfma_f32_16x16x32_bf16(af[m], b1, acc1[m*4+n], 0, 0, 0);
        }
      }
    }
    __syncthreads();
  }

  if constexpr (DUAL) {
    unsigned short* Hp = Hout + (size_t)e*CAP*N + (size_t)mt*128*N + (size_t)nt*128;
#pragma unroll
    for (int m = 0; m < 4; ++m) {
#pragma unroll
      for (int n = 0; n < 4; ++n) {
        f32x4 g = acc0[m*4+n], u = acc1[m*4+n];
#pragma unroll
        for (int r = 0; r < 4; ++r) {
          int row = wm + m*16 + khi*4 + r;
          int col = wn + n*16 + lrow;
          float gv = g[r];
          float hv = gv / (1.f + __expf(-gv)) * u[r];
          Hp[(size_t)row*N + col] = f2b(hv);
        }
      }
    }
  } else {
    float* Fp = Fout + (size_t)e*CAP*N + (size_t)mt*128*N + (size_t)nt*128;
#pragma unroll
    for (int m = 0; m < 4; ++m) {
#pragma unroll
      for (int n = 0; n < 4; ++n) {
        f32x4 v = acc0[m*4+n];
#pragma unroll
        for (int r = 0; r < 4; ++r) {
          int row = wm + m*16 + khi*4 + r;
          int col = wn + n*16 + lrow;
          Fp[(size_t)row*N + col] = v[r];
        }
      }
    }
  }
}

// ---------------- combine ----------------
__global__ __launch_bounds__(192) void combine_kernel(const float* __restrict__ outbuf,
    const int* __restrict__ c1, const int* __restrict__ c2,
    const float* __restrict__ g1, const float* __restrict__ g2,
    float* __restrict__ y) {
  int t = blockIdx.x;
  int q = threadIdx.x;
  float f1 = g1[t], f2 = g2[t];
  int a = c1[t], b = c2[t];
  float4 va = ((const float4*)outbuf)[(size_t)a*(CDIM/4) + q];
  float4 vb = ((const float4*)outbuf)[(size_t)b*(CDIM/4) + q];
  float4 r;
  r.x = f1*va.x + f2*vb.x;
  r.y = f1*va.y + f2*vb.y;
  r.z = f1*va.z + f2*vb.z;
  r.w = f1*va.w + f2*vb.w;
  ((float4*)y)[(size_t)t*(CDIM/4) + q] = r;
}

extern "C" void kernel_launch(void* const* d_in, const int* in_sizes, int n_in,
                              void* d_out, int out_size, void* d_ws, size_t ws_size,
                              hipStream_t stream) {
  const float* x  = (const float*)d_in[0];
  const float* Wr = (const float*)d_in[1];
  const float* Wg = (const float*)d_in[2];
  const float* Wu = (const float*)d_in[3];
  const float* Wp = (const float*)d_in[4];
  float* y = (float*)d_out;

  char* p = (char*)d_ws;
  auto alloc = [&](size_t bytes) { char* r = p; p += (bytes + 255) & ~(size_t)255; return r; };
  unsigned short* WgT = (unsigned short*)alloc((size_t)NEXP*IDIM*CDIM*2);
  unsigned short* WuT = (unsigned short*)alloc((size_t)NEXP*IDIM*CDIM*2);
  unsigned short* WpT = (unsigned short*)alloc((size_t)NEXP*CDIM*IDIM*2);
  unsigned short* ein = (unsigned short*)alloc((size_t)EROWS*CDIM*2);
  unsigned short* h   = (unsigned short*)alloc((size_t)EROWS*IDIM*2);
  float* outbuf = (float*)alloc((size_t)EROWS*CDIM*4);
  float* probs  = (float*)alloc((size_t)NTOK*NEXP*4);
  int* idx1 = (int*)alloc(NTOK*4);
  int* idx2 = (int*)alloc(NTOK*4);
  int* c1   = (int*)alloc(NTOK*4);
  int* c2   = (int*)alloc(NTOK*4);
  float* g1r = (float*)alloc(NTOK*4);
  float* g2r = (float*)alloc(NTOK*4);
  float* g1o = (float*)alloc(NTOK*4);
  float* g2o = (float*)alloc(NTOK*4);
  int* bufmap = (int*)alloc(EROWS*4);

  size_t required = (size_t)(p - (char*)d_ws);
  if (ws_size < required) return;   // fail visibly (output stays poisoned) rather than corrupt

  hipMemsetAsync(bufmap, 0xFF, EROWS*sizeof(int), stream);

  transpose_cvt<<<NEXP*(CDIM/32)*(IDIM/32), 256, 0, stream>>>(Wg, WgT, CDIM, IDIM);
  transpose_cvt<<<NEXP*(CDIM/32)*(IDIM/32), 256, 0, stream>>>(Wu, WuT, CDIM, IDIM);
  transpose_cvt<<<NEXP*(IDIM/32)*(CDIM/32), 256, 0, stream>>>(Wp, WpT, IDIM, CDIM);

  router_kernel<<<NTOK/4, 256, 0, stream>>>(x, Wr, probs, idx1, idx2, g1r, g2r);
  scan_kernel<<<1, 1024, 0, stream>>>(idx1, idx2, g1r, g2r, probs, bufmap,
                                      c1, c2, g1o, g2o, y + (size_t)NTOK*CDIM);
  dispatch_kernel<<<EROWS, 192, 0, stream>>>(x, bufmap, ein);

  gemm_bt<CDIM, true, true><<<NEXP*10*(IDIM/128), 256, 0, stream>>>(
      ein, WgT, WuT, h, nullptr, IDIM/128, IDIM);
  gemm_bt<IDIM, false, false><<<NEXP*10*(CDIM/128), 256, 0, stream>>>(
      h, WpT, nullptr, nullptr, outbuf, CDIM/128, CDIM);

  combine_kernel<<<NTOK, 192, 0, stream>>>(outbuf, c1, c2, g1o, g2o, y);
}

// Round 2
// 317.050 us; speedup vs baseline: 1.0330x; 1.0330x over previous
//
#include <hip/hip_runtime.h>
#include <cstdint>
#include <cstddef>

#define NTOK 8192
#define NEXP 8
#define CAP 1280
#define CDIM 768
#define IDIM 3072
#define EROWS (NEXP*CAP)   /* 10240 */

typedef __attribute__((ext_vector_type(8))) short short8;
typedef __attribute__((ext_vector_type(4))) float f32x4;
typedef __attribute__((ext_vector_type(4))) unsigned short us4;

__device__ __forceinline__ unsigned short f2b(float f) {
  unsigned u = __builtin_bit_cast(unsigned, f);
  u += 0x7FFFu + ((u >> 16) & 1u);          // round-to-nearest-even
  return (unsigned short)(u >> 16);
}

// ---------------- weight transpose + f32->bf16 convert (Wp) ----------------
// src: [E][R][S] f32  ->  dst: [E][S][R] bf16
__global__ __launch_bounds__(256) void transpose_cvt(const float* __restrict__ src,
    unsigned short* __restrict__ dst, int R, int S) {
  int tilesS = S >> 5, tilesR = R >> 5;
  int perE = tilesR * tilesS;
  int e = blockIdx.x / perE;
  int rem = blockIdx.x % perE;
  int rt = rem / tilesS, st = rem % tilesS;
  const float* se = src + (size_t)e*R*S + ((size_t)rt*32)*S + st*32;
  unsigned short* de = dst + (size_t)e*R*S + ((size_t)st*32)*R + rt*32;
  __shared__ float tile[32][33];
  int tx = threadIdx.x & 31, ty = threadIdx.x >> 5;   // ty 0..7
#pragma unroll
  for (int k = 0; k < 4; ++k) tile[ty + 8*k][tx] = se[(size_t)(ty + 8*k)*S + tx];
  __syncthreads();
#pragma unroll
  for (int k = 0; k < 4; ++k) de[(size_t)(ty + 8*k)*R + tx] = f2b(tile[tx][ty + 8*k]);
}

// ---------------- Wg+Wu -> interleaved-transposed combined Wgu ----------------
// Wg[e][c][i], Wu[e][c][i] f32 -> Wgu[e][n'][c] bf16 where
//   n'(Wg col i) = 32*(i>>4) + (i&15);  n'(Wu col i) = n'(Wg) + 16
// so 16-col blocks alternate g,u along the 6144-wide combined N.
__global__ __launch_bounds__(256) void wgu_cvt(const float* __restrict__ Wg,
    const float* __restrict__ Wu, unsigned short* __restrict__ Wgu) {
  const int tilesR = CDIM/32, tilesS = IDIM/32;    // 24, 96
  const int perE = tilesR * tilesS;
  int sel = blockIdx.x / (NEXP*perE);
  int rem = blockIdx.x % (NEXP*perE);
  int e = rem / perE; int r2 = rem % perE;
  int rt = r2 / tilesS, st = r2 % tilesS;
  const float* src = (sel ? Wu : Wg) + (size_t)e*CDIM*IDIM + ((size_t)rt*32)*IDIM + st*32;
  __shared__ float tile[32][33];
  int tx = threadIdx.x & 31, ty = threadIdx.x >> 5;
#pragma unroll
  for (int k = 0; k < 4; ++k) tile[ty + 8*k][tx] = src[(size_t)(ty + 8*k)*IDIM + tx];
  __syncthreads();
  unsigned short* dstE = Wgu + (size_t)e*(2*IDIM)*CDIM;
#pragma unroll
  for (int k = 0; k < 4; ++k) {
    int i = st*32 + ty + 8*k;
    int np = 32*(i>>4) + (i&15) + sel*16;
    dstE[(size_t)np*CDIM + rt*32 + tx] = f2b(tile[tx][ty + 8*k]);
  }
}

// ---------------- router: logits, softmax, top-2, raw gates ----------------
__global__ __launch_bounds__(256) void router_kernel(const float* __restrict__ x,
    const float* __restrict__ Wr, float* __restrict__ probs,
    int* __restrict__ idx1, int* __restrict__ idx2,
    float* __restrict__ g1r, float* __restrict__ g2r) {
  __shared__ float WrT[NEXP*CDIM];
  for (int i = threadIdx.x; i < NEXP*CDIM; i += 256) {
    int c = i >> 3, e = i & 7;
    WrT[e*CDIM + c] = Wr[i];
  }
  __syncthreads();
  int w = threadIdx.x >> 6, l = threadIdx.x & 63;
  int t = blockIdx.x*4 + w;
  float acc[NEXP];
#pragma unroll
  for (int e = 0; e < NEXP; ++e) acc[e] = 0.f;
  for (int k = 0; k < CDIM/64; ++k) {
    float xv = x[(size_t)t*CDIM + k*64 + l];
#pragma unroll
    for (int e = 0; e < NEXP; ++e) acc[e] += xv * WrT[e*CDIM + k*64 + l];
  }
#pragma unroll
  for (int off = 32; off > 0; off >>= 1) {
#pragma unroll
    for (int e = 0; e < NEXP; ++e) acc[e] += __shfl_xor(acc[e], off);
  }
  if (l == 0) {
    float m = acc[0];
#pragma unroll
    for (int e = 1; e < NEXP; ++e) m = fmaxf(m, acc[e]);
    float p[NEXP]; float s = 0.f;
#pragma unroll
    for (int e = 0; e < NEXP; ++e) { p[e] = expf(acc[e] - m); s += p[e]; }
    float inv = 1.f / s;
#pragma unroll
    for (int e = 0; e < NEXP; ++e) { p[e] *= inv; probs[(size_t)t*NEXP + e] = p[e]; }
    int i1 = 0; float b1 = p[0];
#pragma unroll
    for (int e = 1; e < NEXP; ++e) if (p[e] > b1) { b1 = p[e]; i1 = e; }
    int i2 = -1; float b2 = -1e30f;
#pragma unroll
    for (int e = 0; e < NEXP; ++e) if (e != i1 && p[e] > b2) { b2 = p[e]; i2 = e; }
    float gs = fmaxf(b1 + b2, 1e-9f);
    g1r[t] = b1 / gs; g2r[t] = b2 / gs;
    idx1[t] = i1; idx2[t] = i2;
  }
}

// ---------------- scan: capacity positions, bufmap, gates, aux ----------------
__global__ __launch_bounds__(1024) void scan_kernel(
    const int* __restrict__ idx1, const int* __restrict__ idx2,
    const float* __restrict__ g1r, const float* __restrict__ g2r,
    const float* __restrict__ probs,
    int* __restrict__ bufmap,          // pre-memset to -1
    int* __restrict__ c1o, int* __restrict__ c2o,
    float* __restrict__ g1o, float* __restrict__ g2o,
    float* __restrict__ aux_out) {
  __shared__ unsigned int scanbuf[1024][9];
  __shared__ unsigned int totals[NEXP];
  int tid = threadIdx.x;
  int e1[8], e2[8];
  unsigned int cnt[NEXP];
#pragma unroll
  for (int k = 0; k < NEXP; ++k) cnt[k] = 0;
  for (int j = 0; j < 8; ++j) {
    int t = tid*8 + j;
    e1[j] = idx1[t]; e2[j] = idx2[t];
    cnt[e1[j]] += 1u;            // low 16: first-choice count
    cnt[e2[j]] += (1u << 16);    // high 16: second-choice count
  }
#pragma unroll
  for (int k = 0; k < NEXP; ++k) scanbuf[tid][k] = cnt[k];
  unsigned int run[NEXP];
#pragma unroll
  for (int k = 0; k < NEXP; ++k) run[k] = cnt[k];
  __syncthreads();
  for (int off = 1; off < 1024; off <<= 1) {
    unsigned int add[NEXP];
#pragma unroll
    for (int k = 0; k < NEXP; ++k) add[k] = 0;
    if (tid >= off) {
#pragma unroll
      for (int k = 0; k < NEXP; ++k) add[k] = scanbuf[tid - off][k];
    }
    __syncthreads();
#pragma unroll
    for (int k = 0; k < NEXP; ++k) { run[k] += add[k]; scanbuf[tid][k] = run[k]; }
    __syncthreads();
  }
  if (tid == 1023) {
#pragma unroll
    for (int k = 0; k < NEXP; ++k) totals[k] = run[k];
  }
  __syncthreads();
  unsigned int excl[NEXP];
#pragma unroll
  for (int k = 0; k < NEXP; ++k) excl[k] = run[k] - cnt[k];
  int cnt1c[NEXP];
#pragma unroll
  for (int k = 0; k < NEXP; ++k) cnt1c[k] = min((int)(totals[k] & 0xFFFFu), CAP);

  for (int j = 0; j < 8; ++j) {
    int t = tid*8 + j;
    int a = e1[j];
    int pos1 = (int)(excl[a] & 0xFFFFu); excl[a] += 1u;
    int slot1 = a*CAP + pos1;
    bool m1 = pos1 < CAP;
    if (m1) bufmap[slot1] = t;
    int b = e2[j];
    int pos2 = (int)(excl[b] >> 16) + cnt1c[b]; excl[b] += (1u << 16);
    int slot2 = b*CAP + pos2;
    bool m2 = pos2 < CAP;
    if (m2) bufmap[slot2] = t;
    float G1 = m1 ? g1r[t] : 0.f;
    float G2 = m2 ? g2r[t] : 0.f;
    float den = fmaxf(G1 + G2, 1e-9f);
    g1o[t] = G1 / den; g2o[t] = G2 / den;
    c1o[t] = min(slot1, EROWS - 1);
    c2o[t] = min(slot2, EROWS - 1);
  }

  // deterministic importance reduction
  float imp[NEXP];
#pragma unroll
  for (int k = 0; k < NEXP; ++k) imp[k] = 0.f;
  for (int j = 0; j < 8; ++j) {
    int t = tid*8 + j;
    const float4* pr = (const float4*)(probs + (size_t)t*NEXP);
    float4 a0 = pr[0], a1 = pr[1];
    imp[0] += a0.x; imp[1] += a0.y; imp[2] += a0.z; imp[3] += a0.w;
    imp[4] += a1.x; imp[5] += a1.y; imp[6] += a1.z; imp[7] += a1.w;
  }
  __syncthreads();
  float* fbuf = (float*)&scanbuf[0][0];
#pragma unroll
  for (int k = 0; k < NEXP; ++k) fbuf[tid*9 + k] = imp[k];
  __syncthreads();
  for (int s = 512; s >= 1; s >>= 1) {
    if (tid < s) {
#pragma unroll
      for (int k = 0; k < NEXP; ++k) fbuf[tid*9 + k] += fbuf[(tid + s)*9 + k];
    }
    __syncthreads();
  }
  if (tid == 0) {
    float aux = 0.f;
#pragma unroll
    for (int k = 0; k < NEXP; ++k) {
      float importance = fbuf[k] / (float)NTOK;
      float loadk = (float)((totals[k] & 0xFFFFu) + (totals[k] >> 16)) / ((float)NTOK * 2.0f);
      aux += importance * loadk;
    }
    aux_out[0] = aux * (float)NEXP * 0.01f;
  }
}

// ---------------- dispatch: gather x -> ein (bf16) ----------------
__global__ __launch_bounds__(192) void dispatch_kernel(const float* __restrict__ x,
    const int* __restrict__ bufmap, unsigned short* __restrict__ ein) {
  int r = blockIdx.x;
  int t = bufmap[r];
  int q = threadIdx.x;   // 0..191, 4 floats each
  float4 v = make_float4(0.f, 0.f, 0.f, 0.f);
  if (t >= 0) v = ((const float4*)x)[(size_t)t*(CDIM/4) + q];
  us4 o;
  o.x = f2b(v.x); o.y = f2b(v.y); o.z = f2b(v.z); o.w = f2b(v.w);
  ((us4*)ein)[(size_t)r*(CDIM/4) + q] = o;
}

// =============== GEMM1: 256x256 8-phase, dual-output via interleaved Wgu ======
// A = ein [8][1280][768] bf16 (K contiguous); B = Wgu [8][6144][768] bf16.
// Output h[10240][3072] bf16 = silu(x*Wg) * (x*Wu); g/u interleaved per 16 cols.
// Schedule: 2 LDS K-tile buffers (X=even tiles buf0, Y=odd buf1), 8 phases/iter,
// counted vmcnt (4 @ph4, 6 @ph8), raw s_barrier (no compiler vmcnt0 drain).
#define BAR  asm volatile("s_barrier" ::: "memory")
#define VMW(N) asm volatile("s_waitcnt vmcnt(" #N ")" ::: "memory")
#define P1 __builtin_amdgcn_s_setprio(1)
#define P0 __builtin_amdgcn_s_setprio(0)

template<int KD>
__global__ __launch_bounds__(512, 2) void gemm1_8ph(
    const unsigned short* __restrict__ A,
    const unsigned short* __restrict__ Bw,
    unsigned short* __restrict__ H) {
  constexpr int NT = KD/64;
  constexpr int NITER = NT/2;
  __shared__ unsigned short lds[65536];   // 128 KiB: 2 buf x (A 32K + B 32K)

  const int bid = blockIdx.x;
  const int chunk = gridDim.x >> 3;              // 960/8 = 120 = one expert per XCD
  const int tile = (bid & 7)*chunk + (bid >> 3);
  const int e = tile / 120;
  const int rem = tile % 120;
  const int nt = rem / 5, mt = rem % 5;

  const int tid = threadIdx.x;
  const int l = tid & 63, wid = tid >> 6;
  const int wr = wid >> 2, wc = wid & 3;
  const int lrow = l & 15, khi = l >> 4;

  const unsigned short* Ab = A  + (size_t)e*CAP*KD    + (size_t)mt*256*KD;
  const unsigned short* Bb = Bw + (size_t)e*(2*IDIM)*KD + (size_t)nt*256*KD;

  // staging: linear LDS dest, inverse-swizzled global source (rule 21)
  const int srow = tid >> 3;                     // 0..63
  const int scol = (tid & 7) ^ (srow & 7);
  const size_t lane_off = (size_t)srow*KD + scol*8;
  const int lds_st = wid*512;                    // wave-uniform dest (ushorts)

#define STG(buf, op, half, kt) do { \
    const unsigned short* s_ = ((op) ? Bb : Ab) + lane_off + (size_t)(half)*128*KD + (size_t)(kt)*64; \
    unsigned short* d_ = (unsigned short*)lds + (buf)*32768 + (op)*16384 + (half)*8192 + lds_st; \
    __builtin_amdgcn_global_load_lds((const __attribute__((address_space(1))) void*)s_, \
        (__attribute__((address_space(3))) void*)d_, 16, 0, 0); \
    __builtin_amdgcn_global_load_lds((const __attribute__((address_space(1))) void*)(s_ + (size_t)64*KD), \
        (__attribute__((address_space(3))) void*)(d_ + 4096), 16, 0, 0); \
  } while(0)

  // fragment read offsets (ushort units); swizzled 16B slot = (c ^ (row&7))
  const int swz0 = ((khi    ) ^ (lrow & 7)) * 8;
  const int swz1 = ((4 + khi) ^ (lrow & 7)) * 8;
  const int abase = wr*8192 + lrow*64;                       // + buf*32768 + m*1024
  const int bbase = 16384 + (wc>>1)*8192 + ((wc&1)*64 + lrow)*64;  // + buf*32768 + n*1024

#define LDA(buf, dst, mb) do { _Pragma("unroll") for (int m_=0;m_<4;++m_) { \
    dst[m_][0] = *(const short8*)(lds + (buf)*32768 + abase + ((mb)+m_)*1024 + swz0); \
    dst[m_][1] = *(const short8*)(lds + (buf)*32768 + abase + ((mb)+m_)*1024 + swz1); } } while(0)
#define LDB(buf, dst, nb) do { _Pragma("unroll") for (int n_=0;n_<2;++n_) { \
    dst[n_][0] = *(const short8*)(lds + (buf)*32768 + bbase + ((nb)+n_)*1024 + swz0); \
    dst[n_][1] = *(const short8*)(lds + (buf)*32768 + bbase + ((nb)+n_)*1024 + swz1); } } while(0)
#define QUAD(af, bf, mb, nb) do { _Pragma("unroll") for (int n_=0;n_<2;++n_) \
    _Pragma("unroll") for (int m_=0;m_<4;++m_) { \
      acc[(mb)+m_][(nb)+n_] = __builtin_amdgcn_mfma_f32_16x16x32_bf16(af[m_][0], bf[n_][0], acc[(mb)+m_][(nb)+n_], 0,0,0); \
      acc[(mb)+m_][(nb)+n_] = __builtin_amdgcn_mfma_f32_16x16x32_bf16(af[m_][1], bf[n_][1], acc[(mb)+m_][(nb)+n_], 0,0,0); } } while(0)

  f32x4 acc[8][4];
#pragma unroll
  for (int i = 0; i < 8; ++i)
#pragma unroll
    for (int j = 0; j < 4; ++j) acc[i][j] = (f32x4){0.f,0.f,0.f,0.f};

  short8 a[4][2], bl[2][2], bh[2][2];

  // prologue: X <- tile0 (all 4 halves), Y <- tile1 (B0,B1,A0)
  STG(0,0,0,0); STG(0,0,1,0); STG(0,1,0,0); STG(0,1,1,0);
  STG(1,1,0,1); STG(1,1,1,1); STG(1,0,0,1);
  VMW(6);      // X's 8 loads landed; Y's 6 may remain in flight
  BAR;

  // iteration body: computes tiles tX (buf0) and tX+1 (buf1);
  // stages: ph1 Y.A1<-tY, ph3..6 X<-t2, ph7/8 Y(B0,B1,A0)<-t3.
#define ITER(tY, t2, t3, DOS2, VM4, VM8) \
    LDA(0,a,0); LDB(0,bl,0); STG(1,0,1,(tY)); \
    BAR; P1; QUAD(a,bl,0,0); P0; BAR; \
    LDB(0,bh,2); \
    BAR; P1; QUAD(a,bh,0,2); P0; BAR; \
    LDA(0,a,4); if (DOS2) STG(0,1,0,(t2)); \
    BAR; P1; QUAD(a,bh,4,2); P0; BAR; \
    if (DOS2) STG(0,1,1,(t2)); VM4; \
    BAR; P1; QUAD(a,bl,4,0); P0; BAR; \
    LDA(1,a,0); LDB(1,bl,0); if (DOS2) STG(0,0,0,(t2)); \
    BAR; P1; QUAD(a,bl,0,0); P0; BAR; \
    LDB(1,bh,2); if (DOS2) STG(0,0,1,(t2)); \
    BAR; P1; QUAD(a,bh,0,2); P0; BAR; \
    LDA(1,a,4); if (DOS2) STG(1,1,0,(t3)); \
    BAR; P1; QUAD(a,bh,4,2); P0; BAR; \
    if (DOS2) { STG(1,1,1,(t3)); STG(1,0,0,(t3)); } VM8; \
    BAR; P1; QUAD(a,bl,4,0); P0; BAR;

#pragma unroll 1
  for (int i = 0; i < NITER-1; ++i) {
    const int tY = 2*i+1, t2 = 2*i+2, t3 = 2*i+3;
    ITER(tY, t2, t3, true, VMW(4), VMW(6));
  }
  // tail iteration: only ph1's Y.A1 stage (tile NT-1); drain before ph5.
  ITER(NT-1, 0, 0, false, VMW(0), VMW(0));

#undef ITER
#undef QUAD
#undef LDB
#undef LDA
#undef STG

  // epilogue: pair (n even = g, n odd = u) -> h = silu(g)*u, bf16
  const size_t rb = (size_t)e*CAP + (size_t)mt*256 + wr*128 + khi*4;
  const size_t cb = (size_t)nt*128 + wc*32 + lrow;
#pragma unroll
  for (int m = 0; m < 8; ++m)
#pragma unroll
    for (int p = 0; p < 2; ++p) {
      f32x4 g = acc[m][2*p], u = acc[m][2*p+1];
#pragma unroll
      for (int r = 0; r < 4; ++r) {
        float gv = g[r];
        float hv = gv / (1.f + __expf(-gv)) * u[r];
        H[(rb + m*16 + r)*(size_t)IDIM + cb + p*16] = f2b(hv);
      }
    }
}

// ---------------- m97-style bf16 MFMA GEMM (A[M,K] x B^T[N,K]) — GEMM2 -------
template<int K, bool DUAL, bool NOUTER>
__global__ __launch_bounds__(256, 2) void gemm_bt(
    const unsigned short* __restrict__ A,
    const unsigned short* __restrict__ B0,
    const unsigned short* __restrict__ B1,
    unsigned short* __restrict__ Hout,
    float* __restrict__ Fout,
    int Ntiles, int N) {
  constexpr int MT = 10;
  int chunk = gridDim.x >> 3;
  int bid = blockIdx.x;
  int tile = (bid & 7)*chunk + (bid >> 3);
  int perE = MT * Ntiles;
  int e = tile / perE, rem = tile % perE;
  int mt, nt;
  if (NOUTER) { nt = rem / MT; mt = rem % MT; }
  else        { mt = rem / Ntiles; nt = rem % Ntiles; }

  const unsigned short* Ae  = A  + (size_t)e*CAP*K + (size_t)mt*128*K;
  const unsigned short* B0e = B0 + (size_t)e*N*K   + (size_t)nt*128*K;
  const unsigned short* B1e = nullptr;
  if constexpr (DUAL) B1e = B1 + (size_t)e*N*K + (size_t)nt*128*K;

  __shared__ unsigned short Alds[128*64];
  __shared__ unsigned short B0lds[128*64];
  __shared__ unsigned short B1lds[DUAL ? 128*64 : 8];

  int tid = threadIdx.x;
  int l = tid & 63, w = tid >> 6;
  int rbase = w*8 + (l >> 3);
  int csrc  = (l & 7) ^ ((l >> 3) & 7);
  size_t gbase = (size_t)rbase*K + (size_t)csrc*8;
  int ldsoff = w*512;

  f32x4 acc0[16];
  f32x4 acc1[DUAL ? 16 : 1];
#pragma unroll
  for (int i = 0; i < 16; ++i) acc0[i] = (f32x4){0.f,0.f,0.f,0.f};
  if constexpr (DUAL) {
#pragma unroll
    for (int i = 0; i < 16; ++i) acc1[i] = (f32x4){0.f,0.f,0.f,0.f};
  }

  int wm = (w >> 1)*64, wn = (w & 1)*64;
  int lrow = l & 15, khi = l >> 4;

  for (int kt = 0; kt < K/64; ++kt) {
    const unsigned short* Ag  = Ae  + gbase + (size_t)kt*64;
    const unsigned short* Bg0 = B0e + gbase + (size_t)kt*64;
#pragma unroll
    for (int q = 0; q < 4; ++q) {
      __builtin_amdgcn_global_load_lds(
          (const __attribute__((address_space(1))) void*)(Ag + (size_t)q*32*K),
          (__attribute__((address_space(3))) void*)(Alds + ldsoff + q*2048), 16, 0, 0);
    }
#pragma unroll
    for (int q = 0; q < 4; ++q) {
      __builtin_amdgcn_global_load_lds(
          (const __attribute__((address_space(1))) void*)(Bg0 + (size_t)q*32*K),
          (__attribute__((address_space(3))) void*)(B0lds + ldsoff + q*2048), 16, 0, 0);
    }
    if constexpr (DUAL) {
      const unsigned short* Bg1 = B1e + gbase + (size_t)kt*64;
#pragma unroll
      for (int q = 0; q < 4; ++q) {
        __builtin_amdgcn_global_load_lds(
            (const __attribute__((address_space(1))) void*)(Bg1 + (size_t)q*32*K),
            (__attribute__((address_space(3))) void*)(B1lds + ldsoff + q*2048), 16, 0, 0);
      }
    }
    __syncthreads();
#pragma unroll
    for (int kk = 0; kk < 2; ++kk) {
      int cs = (kk*4 + khi) ^ (l & 7);
      short8 af[4];
#pragma unroll
      for (int m = 0; m < 4; ++m) {
        int row = wm + m*16 + lrow;
        af[m] = *(const short8*)(Alds + row*64 + cs*8);
      }
#pragma unroll
      for (int n = 0; n < 4; ++n) {
        int rowb = wn + n*16 + lrow;
        short8 b0 = *(const short8*)(B0lds + rowb*64 + cs*8);
#pragma unroll
        for (int m = 0; m < 4; ++m)
          acc0[m*4+n] = __builtin_amdgcn_mfma_f32_16x16x32_bf16(af[m], b0, acc0[m*4+n], 0, 0, 0);
        if constexpr (DUAL) {
          short8 b1 = *(const short8*)(B1lds + rowb*64 + cs*8);
#pragma unroll
          for (int m = 0; m < 4; ++m)
            acc1[m*4+n] = __builtin_amdgcn_mfma_f32_16x16x32_bf16(af[m], b1, acc1[m*4+n], 0, 0, 0);
        }
      }
    }
    __syncthreads();
  }

  if constexpr (DUAL) {
    unsigned short* Hp = Hout + (size_t)e*CAP*N + (size_t)mt*128*N + (size_t)nt*128;
#pragma unroll
    for (int m = 0; m < 4; ++m) {
#pragma unroll
      for (int n = 0; n < 4; ++n) {
        f32x4 g = acc0[m*4+n], u = acc1[m*4+n];
#pragma unroll
        for (int r = 0; r < 4; ++r) {
          int row = wm + m*16 + khi*4 + r;
          int col = wn + n*16 + lrow;
          float gv = g[r];
          float hv = gv / (1.f + __expf(-gv)) * u[r];
          Hp[(size_t)row*N + col] = f2b(hv);
        }
      }
    }
  } else {
    float* Fp = Fout + (size_t)e*CAP*N + (size_t)mt*128*N + (size_t)nt*128;
#pragma unroll
    for (int m = 0; m < 4; ++m) {
#pragma unroll
      for (int n = 0; n < 4; ++n) {
        f32x4 v = acc0[m*4+n];
#pragma unroll
        for (int r = 0; r < 4; ++r) {
          int row = wm + m*16 + khi*4 + r;
          int col = wn + n*16 + lrow;
          Fp[(size_t)row*N + col] = v[r];
        }
      }
    }
  }
}

// ---------------- combine ----------------
__global__ __launch_bounds__(192) void combine_kernel(const float* __restrict__ outbuf,
    const int* __restrict__ c1, const int* __restrict__ c2,
    const float* __restrict__ g1, const float* __restrict__ g2,
    float* __restrict__ y) {
  int t = blockIdx.x;
  int q = threadIdx.x;
  float f1 = g1[t], f2 = g2[t];
  int a = c1[t], b = c2[t];
  float4 va = ((const float4*)outbuf)[(size_t)a*(CDIM/4) + q];
  float4 vb = ((const float4*)outbuf)[(size_t)b*(CDIM/4) + q];
  float4 r;
  r.x = f1*va.x + f2*vb.x;
  r.y = f1*va.y + f2*vb.y;
  r.z = f1*va.z + f2*vb.z;
  r.w = f1*va.w + f2*vb.w;
  ((float4*)y)[(size_t)t*(CDIM/4) + q] = r;
}

extern "C" void kernel_launch(void* const* d_in, const int* in_sizes, int n_in,
                              void* d_out, int out_size, void* d_ws, size_t ws_size,
                              hipStream_t stream) {
  const float* x  = (const float*)d_in[0];
  const float* Wr = (const float*)d_in[1];
  const float* Wg = (const float*)d_in[2];
  const float* Wu = (const float*)d_in[3];
  const float* Wp = (const float*)d_in[4];
  float* y = (float*)d_out;

  char* p = (char*)d_ws;
  auto alloc = [&](size_t bytes) { char* r = p; p += (bytes + 255) & ~(size_t)255; return r; };
  unsigned short* WguT = (unsigned short*)alloc((size_t)NEXP*2*IDIM*CDIM*2);
  unsigned short* WpT  = (unsigned short*)alloc((size_t)NEXP*CDIM*IDIM*2);
  unsigned short* ein  = (unsigned short*)alloc((size_t)EROWS*CDIM*2);
  unsigned short* h    = (unsigned short*)alloc((size_t)EROWS*IDIM*2);
  float* outbuf = (float*)alloc((size_t)EROWS*CDIM*4);
  float* probs  = (float*)alloc((size_t)NTOK*NEXP*4);
  int* idx1 = (int*)alloc(NTOK*4);
  int* idx2 = (int*)alloc(NTOK*4);
  int* c1   = (int*)alloc(NTOK*4);
  int* c2   = (int*)alloc(NTOK*4);
  float* g1r = (float*)alloc(NTOK*4);
  float* g2r = (float*)alloc(NTOK*4);
  float* g1o = (float*)alloc(NTOK*4);
  float* g2o = (float*)alloc(NTOK*4);
  int* bufmap = (int*)alloc(EROWS*4);

  size_t required = (size_t)(p - (char*)d_ws);
  if (ws_size < required) return;

  hipMemsetAsync(bufmap, 0xFF, EROWS*sizeof(int), stream);

  wgu_cvt<<<2*NEXP*(CDIM/32)*(IDIM/32), 256, 0, stream>>>(Wg, Wu, WguT);
  transpose_cvt<<<NEXP*(IDIM/32)*(CDIM/32), 256, 0, stream>>>(Wp, WpT, IDIM, CDIM);

  router_kernel<<<NTOK/4, 256, 0, stream>>>(x, Wr, probs, idx1, idx2, g1r, g2r);
  scan_kernel<<<1, 1024, 0, stream>>>(idx1, idx2, g1r, g2r, probs, bufmap,
                                      c1, c2, g1o, g2o, y + (size_t)NTOK*CDIM);
  dispatch_kernel<<<EROWS, 192, 0, stream>>>(x, bufmap, ein);

  gemm1_8ph<CDIM><<<NEXP*5*(2*IDIM/256), 512, 0, stream>>>(ein, WguT, h);
  gemm_bt<IDIM, false, false><<<NEXP*10*(CDIM/128), 256, 0, stream>>>(
      h, WpT, nullptr, nullptr, outbuf, CDIM/128, CDIM);

  combine_kernel<<<NTOK, 192, 0, stream>>>(outbuf, c1, c2, g1o, g2o, y);
}

// Round 3
// 316.816 us; speedup vs baseline: 1.0338x; 1.0007x over previous
//
#include <hip/hip_runtime.h>
#include <cstdint>
#include <cstddef>

#define NTOK 8192
#define NEXP 8
#define CAP 1280
#define CDIM 768
#define IDIM 3072
#define EROWS (NEXP*CAP)   /* 10240 */

typedef __attribute__((ext_vector_type(8))) short short8;
typedef __attribute__((ext_vector_type(4))) float f32x4;
typedef __attribute__((ext_vector_type(4))) unsigned short us4;
typedef __attribute__((ext_vector_type(8))) unsigned short us8;

__device__ __forceinline__ unsigned short f2b(float f) {
  unsigned u = __builtin_bit_cast(unsigned, f);
  u += 0x7FFFu + ((u >> 16) & 1u);          // round-to-nearest-even
  return (unsigned short)(u >> 16);
}

// ---------------- 64x64 vectorized transpose + f32->bf16 (Wp) ----------------
// src: [E][R][S] f32 -> dst: [E][S][R] bf16.  float4 reads, us4 writes.
__global__ __launch_bounds__(256) void transpose_cvt64(const float* __restrict__ src,
    unsigned short* __restrict__ dst, int R, int S) {
  int tilesS = S >> 6, tilesR = R >> 6;
  int perE = tilesR * tilesS;
  int e = blockIdx.x / perE;
  int rem = blockIdx.x % perE;
  int rt = rem / tilesS, st = rem % tilesS;
  const float* se = src + (size_t)e*R*S + ((size_t)rt*64)*S + st*64;
  unsigned short* de = dst + (size_t)e*R*S + ((size_t)st*64)*R + rt*64;
  __shared__ float tile[64][65];
  int c4 = (threadIdx.x & 15)*4, rr = threadIdx.x >> 4;   // rr 0..15
#pragma unroll
  for (int p = 0; p < 4; ++p) {
    float4 v = *(const float4*)(se + (size_t)(rr + 16*p)*S + c4);
    tile[rr + 16*p][c4+0] = v.x; tile[rr + 16*p][c4+1] = v.y;
    tile[rr + 16*p][c4+2] = v.z; tile[rr + 16*p][c4+3] = v.w;
  }
  __syncthreads();
#pragma unroll
  for (int p = 0; p < 4; ++p) {
    int s = rr + 16*p;            // out row (src col)
    us4 o;
    o.x = f2b(tile[c4+0][s]); o.y = f2b(tile[c4+1][s]);
    o.z = f2b(tile[c4+2][s]); o.w = f2b(tile[c4+3][s]);
    *(us4*)(de + (size_t)s*R + c4) = o;
  }
}

// ---------------- Wg+Wu -> interleaved-transposed combined Wgu (64x64) -------
// n'(Wg col i) = 32*(i>>4) + (i&15);  n'(Wu col i) = n'(Wg) + 16
__global__ __launch_bounds__(256) void wgu_cvt64(const float* __restrict__ Wg,
    const float* __restrict__ Wu, unsigned short* __restrict__ Wgu) {
  const int tilesR = CDIM/64, tilesS = IDIM/64;    // 12, 48
  const int perE = tilesR * tilesS;
  int sel = blockIdx.x / (NEXP*perE);
  int rem = blockIdx.x % (NEXP*perE);
  int e = rem / perE; int r2 = rem % perE;
  int rt = r2 / tilesS, st = r2 % tilesS;
  const float* se = (sel ? Wu : Wg) + (size_t)e*CDIM*IDIM + ((size_t)rt*64)*IDIM + st*64;
  __shared__ float tile[64][65];
  int c4 = (threadIdx.x & 15)*4, rr = threadIdx.x >> 4;
#pragma unroll
  for (int p = 0; p < 4; ++p) {
    float4 v = *(const float4*)(se + (size_t)(rr + 16*p)*IDIM + c4);
    tile[rr + 16*p][c4+0] = v.x; tile[rr + 16*p][c4+1] = v.y;
    tile[rr + 16*p][c4+2] = v.z; tile[rr + 16*p][c4+3] = v.w;
  }
  __syncthreads();
  unsigned short* dstE = Wgu + (size_t)e*(2*IDIM)*CDIM;
#pragma unroll
  for (int p = 0; p < 4; ++p) {
    int s = rr + 16*p;            // src col within tile; i = st*64 + s
    int np = 128*st + 32*(s>>4) + (s&15) + sel*16;
    us4 o;
    o.x = f2b(tile[c4+0][s]); o.y = f2b(tile[c4+1][s]);
    o.z = f2b(tile[c4+2][s]); o.w = f2b(tile[c4+3][s]);
    *(us4*)(dstE + (size_t)np*CDIM + rt*64 + c4) = o;
  }
}

// ---------------- router: logits, softmax, top-2, raw gates ----------------
__global__ __launch_bounds__(256) void router_kernel(const float* __restrict__ x,
    const float* __restrict__ Wr, float* __restrict__ probs,
    int* __restrict__ idx1, int* __restrict__ idx2,
    float* __restrict__ g1r, float* __restrict__ g2r) {
  __shared__ float WrT[NEXP*CDIM];
  for (int i = threadIdx.x; i < NEXP*CDIM; i += 256) {
    int c = i >> 3, e = i & 7;
    WrT[e*CDIM + c] = Wr[i];
  }
  __syncthreads();
  int w = threadIdx.x >> 6, l = threadIdx.x & 63;
  int t = blockIdx.x*4 + w;
  float acc[NEXP];
#pragma unroll
  for (int e = 0; e < NEXP; ++e) acc[e] = 0.f;
  for (int k = 0; k < CDIM/64; ++k) {
    float xv = x[(size_t)t*CDIM + k*64 + l];
#pragma unroll
    for (int e = 0; e < NEXP; ++e) acc[e] += xv * WrT[e*CDIM + k*64 + l];
  }
#pragma unroll
  for (int off = 32; off > 0; off >>= 1) {
#pragma unroll
    for (int e = 0; e < NEXP; ++e) acc[e] += __shfl_xor(acc[e], off);
  }
  if (l == 0) {
    float m = acc[0];
#pragma unroll
    for (int e = 1; e < NEXP; ++e) m = fmaxf(m, acc[e]);
    float p[NEXP]; float s = 0.f;
#pragma unroll
    for (int e = 0; e < NEXP; ++e) { p[e] = expf(acc[e] - m); s += p[e]; }
    float inv = 1.f / s;
#pragma unroll
    for (int e = 0; e < NEXP; ++e) { p[e] *= inv; probs[(size_t)t*NEXP + e] = p[e]; }
    int i1 = 0; float b1 = p[0];
#pragma unroll
    for (int e = 1; e < NEXP; ++e) if (p[e] > b1) { b1 = p[e]; i1 = e; }
    int i2 = -1; float b2 = -1e30f;
#pragma unroll
    for (int e = 0; e < NEXP; ++e) if (e != i1 && p[e] > b2) { b2 = p[e]; i2 = e; }
    float gs = fmaxf(b1 + b2, 1e-9f);
    g1r[t] = b1 / gs; g2r[t] = b2 / gs;
    idx1[t] = i1; idx2[t] = i2;
  }
}

// ---------------- scan: capacity positions, bufmap, gates, aux ----------------
__global__ __launch_bounds__(1024) void scan_kernel(
    const int* __restrict__ idx1, const int* __restrict__ idx2,
    const float* __restrict__ g1r, const float* __restrict__ g2r,
    const float* __restrict__ probs,
    int* __restrict__ bufmap,          // pre-memset to -1
    int* __restrict__ c1o, int* __restrict__ c2o,
    float* __restrict__ g1o, float* __restrict__ g2o,
    float* __restrict__ aux_out) {
  __shared__ unsigned int scanbuf[1024][9];
  __shared__ unsigned int totals[NEXP];
  int tid = threadIdx.x;
  int e1[8], e2[8];
  unsigned int cnt[NEXP];
#pragma unroll
  for (int k = 0; k < NEXP; ++k) cnt[k] = 0;
  for (int j = 0; j < 8; ++j) {
    int t = tid*8 + j;
    e1[j] = idx1[t]; e2[j] = idx2[t];
    cnt[e1[j]] += 1u;            // low 16: first-choice count
    cnt[e2[j]] += (1u << 16);    // high 16: second-choice count
  }
#pragma unroll
  for (int k = 0; k < NEXP; ++k) scanbuf[tid][k] = cnt[k];
  unsigned int run[NEXP];
#pragma unroll
  for (int k = 0; k < NEXP; ++k) run[k] = cnt[k];
  __syncthreads();
  for (int off = 1; off < 1024; off <<= 1) {
    unsigned int add[NEXP];
#pragma unroll
    for (int k = 0; k < NEXP; ++k) add[k] = 0;
    if (tid >= off) {
#pragma unroll
      for (int k = 0; k < NEXP; ++k) add[k] = scanbuf[tid - off][k];
    }
    __syncthreads();
#pragma unroll
    for (int k = 0; k < NEXP; ++k) { run[k] += add[k]; scanbuf[tid][k] = run[k]; }
    __syncthreads();
  }
  if (tid == 1023) {
#pragma unroll
    for (int k = 0; k < NEXP; ++k) totals[k] = run[k];
  }
  __syncthreads();
  unsigned int excl[NEXP];
#pragma unroll
  for (int k = 0; k < NEXP; ++k) excl[k] = run[k] - cnt[k];
  int cnt1c[NEXP];
#pragma unroll
  for (int k = 0; k < NEXP; ++k) cnt1c[k] = min((int)(totals[k] & 0xFFFFu), CAP);

  for (int j = 0; j < 8; ++j) {
    int t = tid*8 + j;
    int a = e1[j];
    int pos1 = (int)(excl[a] & 0xFFFFu); excl[a] += 1u;
    int slot1 = a*CAP + pos1;
    bool m1 = pos1 < CAP;
    if (m1) bufmap[slot1] = t;
    int b = e2[j];
    int pos2 = (int)(excl[b] >> 16) + cnt1c[b]; excl[b] += (1u << 16);
    int slot2 = b*CAP + pos2;
    bool m2 = pos2 < CAP;
    if (m2) bufmap[slot2] = t;
    float G1 = m1 ? g1r[t] : 0.f;
    float G2 = m2 ? g2r[t] : 0.f;
    float den = fmaxf(G1 + G2, 1e-9f);
    g1o[t] = G1 / den; g2o[t] = G2 / den;
    c1o[t] = min(slot1, EROWS - 1);
    c2o[t] = min(slot2, EROWS - 1);
  }

  // deterministic importance reduction
  float imp[NEXP];
#pragma unroll
  for (int k = 0; k < NEXP; ++k) imp[k] = 0.f;
  for (int j = 0; j < 8; ++j) {
    int t = tid*8 + j;
    const float4* pr = (const float4*)(probs + (size_t)t*NEXP);
    float4 a0 = pr[0], a1 = pr[1];
    imp[0] += a0.x; imp[1] += a0.y; imp[2] += a0.z; imp[3] += a0.w;
    imp[4] += a1.x; imp[5] += a1.y; imp[6] += a1.z; imp[7] += a1.w;
  }
  __syncthreads();
  float* fbuf = (float*)&scanbuf[0][0];
#pragma unroll
  for (int k = 0; k < NEXP; ++k) fbuf[tid*9 + k] = imp[k];
  __syncthreads();
  for (int s = 512; s >= 1; s >>= 1) {
    if (tid < s) {
#pragma unroll
      for (int k = 0; k < NEXP; ++k) fbuf[tid*9 + k] += fbuf[(tid + s)*9 + k];
    }
    __syncthreads();
  }
  if (tid == 0) {
    float aux = 0.f;
#pragma unroll
    for (int k = 0; k < NEXP; ++k) {
      float importance = fbuf[k] / (float)NTOK;
      float loadk = (float)((totals[k] & 0xFFFFu) + (totals[k] >> 16)) / ((float)NTOK * 2.0f);
      aux += importance * loadk;
    }
    aux_out[0] = aux * (float)NEXP * 0.01f;
  }
}

// ---------------- dispatch: gather x -> ein (bf16) ----------------
__global__ __launch_bounds__(192) void dispatch_kernel(const float* __restrict__ x,
    const int* __restrict__ bufmap, unsigned short* __restrict__ ein) {
  int r = blockIdx.x;
  int t = bufmap[r];
  int q = threadIdx.x;   // 0..191, 4 floats each
  float4 v = make_float4(0.f, 0.f, 0.f, 0.f);
  if (t >= 0) v = ((const float4*)x)[(size_t)t*(CDIM/4) + q];
  us4 o;
  o.x = f2b(v.x); o.y = f2b(v.y); o.z = f2b(v.z); o.w = f2b(v.w);
  ((us4*)ein)[(size_t)r*(CDIM/4) + q] = o;
}

// =============== GEMM1: 256x256 8-phase, dual-output via interleaved Wgu ======
#define BAR  asm volatile("s_barrier" ::: "memory")
#define VMW(N) asm volatile("s_waitcnt vmcnt(" #N ")" ::: "memory")
#define P1 __builtin_amdgcn_s_setprio(1)
#define P0 __builtin_amdgcn_s_setprio(0)

template<int KD>
__global__ __launch_bounds__(512, 2) void gemm1_8ph(
    const unsigned short* __restrict__ A,
    const unsigned short* __restrict__ Bw,
    unsigned short* __restrict__ H) {
  constexpr int NT = KD/64;
  constexpr int NITER = NT/2;
  __shared__ unsigned short lds[65536];   // 128 KiB: 2 buf x (A 32K + B 32K)

  const int bid = blockIdx.x;
  const int chunk = gridDim.x >> 3;              // 960/8 = 120 = one expert per XCD
  const int tile = (bid & 7)*chunk + (bid >> 3);
  const int e = tile / 120;
  const int rem = tile % 120;
  const int nt = rem / 5, mt = rem % 5;

  const int tid = threadIdx.x;
  const int l = tid & 63, wid = tid >> 6;
  const int wr = wid >> 2, wc = wid & 3;
  const int lrow = l & 15, khi = l >> 4;

  const unsigned short* Ab = A  + (size_t)e*CAP*KD    + (size_t)mt*256*KD;
  const unsigned short* Bb = Bw + (size_t)e*(2*IDIM)*KD + (size_t)nt*256*KD;

  // staging: linear LDS dest, inverse-swizzled global source (rule 21)
  const int srow = tid >> 3;                     // 0..63
  const int scol = (tid & 7) ^ (srow & 7);
  const size_t lane_off = (size_t)srow*KD + scol*8;
  const int lds_st = wid*512;                    // wave-uniform dest (ushorts)

#define STG(buf, op, half, kt) do { \
    const unsigned short* s_ = ((op) ? Bb : Ab) + lane_off + (size_t)(half)*128*KD + (size_t)(kt)*64; \
    unsigned short* d_ = (unsigned short*)lds + (buf)*32768 + (op)*16384 + (half)*8192 + lds_st; \
    __builtin_amdgcn_global_load_lds((const __attribute__((address_space(1))) void*)s_, \
        (__attribute__((address_space(3))) void*)d_, 16, 0, 0); \
    __builtin_amdgcn_global_load_lds((const __attribute__((address_space(1))) void*)(s_ + (size_t)64*KD), \
        (__attribute__((address_space(3))) void*)(d_ + 4096), 16, 0, 0); \
  } while(0)

  // fragment read offsets (ushort units); swizzled 16B slot = (c ^ (row&7))
  const int swz0 = ((khi    ) ^ (lrow & 7)) * 8;
  const int swz1 = ((4 + khi) ^ (lrow & 7)) * 8;
  const int abase = wr*8192 + lrow*64;                       // + buf*32768 + m*1024
  const int bbase = 16384 + (wc>>1)*8192 + ((wc&1)*64 + lrow)*64;  // + buf*32768 + n*1024

#define LDA(buf, dst, mb) do { _Pragma("unroll") for (int m_=0;m_<4;++m_) { \
    dst[m_][0] = *(const short8*)(lds + (buf)*32768 + abase + ((mb)+m_)*1024 + swz0); \
    dst[m_][1] = *(const short8*)(lds + (buf)*32768 + abase + ((mb)+m_)*1024 + swz1); } } while(0)
#define LDB(buf, dst, nb) do { _Pragma("unroll") for (int n_=0;n_<2;++n_) { \
    dst[n_][0] = *(const short8*)(lds + (buf)*32768 + bbase + ((nb)+n_)*1024 + swz0); \
    dst[n_][1] = *(const short8*)(lds + (buf)*32768 + bbase + ((nb)+n_)*1024 + swz1); } } while(0)
// k-slice outer: dependency distance 8 between MFMAs hitting the same acc
#define QUAD(af, bf, mb, nb) do { _Pragma("unroll") for (int r_=0;r_<2;++r_) \
    _Pragma("unroll") for (int n_=0;n_<2;++n_) \
    _Pragma("unroll") for (int m_=0;m_<4;++m_) \
      acc[(mb)+m_][(nb)+n_] = __builtin_amdgcn_mfma_f32_16x16x32_bf16(af[m_][r_], bf[n_][r_], acc[(mb)+m_][(nb)+n_], 0,0,0); } while(0)

  f32x4 acc[8][4];
#pragma unroll
  for (int i = 0; i < 8; ++i)
#pragma unroll
    for (int j = 0; j < 4; ++j) acc[i][j] = (f32x4){0.f,0.f,0.f,0.f};

  short8 a[4][2], bl[2][2], bh[2][2];

  // prologue: X <- tile0 (all 4 halves), Y <- tile1 (B0,B1,A0)
  STG(0,0,0,0); STG(0,0,1,0); STG(0,1,0,0); STG(0,1,1,0);
  STG(1,1,0,1); STG(1,1,1,1); STG(1,0,0,1);
  VMW(6);      // X's 8 loads landed; Y's 6 may remain in flight
  BAR;

#define ITER(tY, t2, t3, DOS2, VM4, VM8) \
    LDA(0,a,0); LDB(0,bl,0); STG(1,0,1,(tY)); \
    BAR; P1; QUAD(a,bl,0,0); P0; BAR; \
    LDB(0,bh,2); \
    BAR; P1; QUAD(a,bh,0,2); P0; BAR; \
    LDA(0,a,4); if (DOS2) STG(0,1,0,(t2)); \
    BAR; P1; QUAD(a,bh,4,2); P0; BAR; \
    if (DOS2) STG(0,1,1,(t2)); VM4; \
    BAR; P1; QUAD(a,bl,4,0); P0; BAR; \
    LDA(1,a,0); LDB(1,bl,0); if (DOS2) STG(0,0,0,(t2)); \
    BAR; P1; QUAD(a,bl,0,0); P0; BAR; \
    LDB(1,bh,2); if (DOS2) STG(0,0,1,(t2)); \
    BAR; P1; QUAD(a,bh,0,2); P0; BAR; \
    LDA(1,a,4); if (DOS2) STG(1,1,0,(t3)); \
    BAR; P1; QUAD(a,bh,4,2); P0; BAR; \
    if (DOS2) { STG(1,1,1,(t3)); STG(1,0,0,(t3)); } VM8; \
    BAR; P1; QUAD(a,bl,4,0); P0; BAR;

#pragma unroll 1
  for (int i = 0; i < NITER-1; ++i) {
    const int tY = 2*i+1, t2 = 2*i+2, t3 = 2*i+3;
    ITER(tY, t2, t3, true, VMW(4), VMW(6));
  }
  ITER(NT-1, 0, 0, false, VMW(0), VMW(0));

#undef ITER
#undef QUAD
#undef LDB
#undef LDA
#undef STG

  // ---- epilogue: silu(g)*u -> LDS (stride 136 ushorts, 16B-aligned rows) ----
  __syncthreads();
  {
    const int cb0 = wc*32 + lrow;
    const int rb0 = wr*128 + khi*4;
#pragma unroll
    for (int m = 0; m < 8; ++m)
#pragma unroll
      for (int p = 0; p < 2; ++p) {
        f32x4 g = acc[m][2*p], u = acc[m][2*p+1];
#pragma unroll
        for (int r = 0; r < 4; ++r) {
          float gv = g[r];
          float hv = gv / (1.f + __expf(-gv)) * u[r];
          lds[(rb0 + m*16 + r)*136 + cb0 + p*16] = f2b(hv);
        }
      }
  }
  __syncthreads();
  // coalesced write-out: per instr 4 rows x 16 chunks of 16B (256B/row segs)
  const size_t rowg = (size_t)e*CAP + (size_t)mt*256;
  const size_t colg = (size_t)nt*128 + (size_t)(l & 15)*8;
#pragma unroll
  for (int i = 0; i < 8; ++i) {
    int row = wid*32 + i*4 + (l >> 4);
    us8 v = *(const us8*)(lds + row*136 + (l & 15)*8);
    *(us8*)(H + (rowg + row)*(size_t)IDIM + colg) = v;
  }
}

// ---------------- m97-style bf16 MFMA GEMM (A[M,K] x B^T[N,K]) — GEMM2 -------
template<int K, bool NOUTER>
__global__ __launch_bounds__(256, 2) void gemm_bt(
    const unsigned short* __restrict__ A,
    const unsigned short* __restrict__ B0,
    float* __restrict__ Fout,
    int Ntiles, int N) {
  constexpr int MT = 10;
  int chunk = gridDim.x >> 3;
  int bid = blockIdx.x;
  int tile = (bid & 7)*chunk + (bid >> 3);
  int perE = MT * Ntiles;
  int e = tile / perE, rem = tile % perE;
  int mt, nt;
  if (NOUTER) { nt = rem / MT; mt = rem % MT; }
  else        { mt = rem / Ntiles; nt = rem % Ntiles; }

  const unsigned short* Ae  = A  + (size_t)e*CAP*K + (size_t)mt*128*K;
  const unsigned short* B0e = B0 + (size_t)e*N*K   + (size_t)nt*128*K;

  __shared__ unsigned short Alds[128*64];
  __shared__ unsigned short B0lds[128*64];

  int tid = threadIdx.x;
  int l = tid & 63, w = tid >> 6;
  int rbase = w*8 + (l >> 3);
  int csrc  = (l & 7) ^ ((l >> 3) & 7);
  size_t gbase = (size_t)rbase*K + (size_t)csrc*8;
  int ldsoff = w*512;

  f32x4 acc0[16];
#pragma unroll
  for (int i = 0; i < 16; ++i) acc0[i] = (f32x4){0.f,0.f,0.f,0.f};

  int wm = (w >> 1)*64, wn = (w & 1)*64;
  int lrow = l & 15, khi = l >> 4;

  for (int kt = 0; kt < K/64; ++kt) {
    const unsigned short* Ag  = Ae  + gbase + (size_t)kt*64;
    const unsigned short* Bg0 = B0e + gbase + (size_t)kt*64;
#pragma unroll
    for (int q = 0; q < 4; ++q) {
      __builtin_amdgcn_global_load_lds(
          (const __attribute__((address_space(1))) void*)(Ag + (size_t)q*32*K),
          (__attribute__((address_space(3))) void*)(Alds + ldsoff + q*2048), 16, 0, 0);
    }
#pragma unroll
    for (int q = 0; q < 4; ++q) {
      __builtin_amdgcn_global_load_lds(
          (const __attribute__((address_space(1))) void*)(Bg0 + (size_t)q*32*K),
          (__attribute__((address_space(3))) void*)(B0lds + ldsoff + q*2048), 16, 0, 0);
    }
    __syncthreads();
#pragma unroll
    for (int kk = 0; kk < 2; ++kk) {
      int cs = (kk*4 + khi) ^ (l & 7);
      short8 af[4];
#pragma unroll
      for (int m = 0; m < 4; ++m) {
        int row = wm + m*16 + lrow;
        af[m] = *(const short8*)(Alds + row*64 + cs*8);
      }
#pragma unroll
      for (int n = 0; n < 4; ++n) {
        int rowb = wn + n*16 + lrow;
        short8 b0 = *(const short8*)(B0lds + rowb*64 + cs*8);
#pragma unroll
        for (int m = 0; m < 4; ++m)
          acc0[m*4+n] = __builtin_amdgcn_mfma_f32_16x16x32_bf16(af[m], b0, acc0[m*4+n], 0, 0, 0);
      }
    }
    __syncthreads();
  }

  float* Fp = Fout + (size_t)e*CAP*N + (size_t)mt*128*N + (size_t)nt*128;
#pragma unroll
  for (int m = 0; m < 4; ++m) {
#pragma unroll
    for (int n = 0; n < 4; ++n) {
      f32x4 v = acc0[m*4+n];
#pragma unroll
      for (int r = 0; r < 4; ++r) {
        int row = wm + m*16 + khi*4 + r;
        int col = wn + n*16 + lrow;
        Fp[(size_t)row*N + col] = v[r];
      }
    }
  }
}

// ---------------- combine ----------------
__global__ __launch_bounds__(192) void combine_kernel(const float* __restrict__ outbuf,
    const int* __restrict__ c1, const int* __restrict__ c2,
    const float* __restrict__ g1, const float* __restrict__ g2,
    float* __restrict__ y) {
  int t = blockIdx.x;
  int q = threadIdx.x;
  float f1 = g1[t], f2 = g2[t];
  int a = c1[t], b = c2[t];
  float4 va = ((const float4*)outbuf)[(size_t)a*(CDIM/4) + q];
  float4 vb = ((const float4*)outbuf)[(size_t)b*(CDIM/4) + q];
  float4 r;
  r.x = f1*va.x + f2*vb.x;
  r.y = f1*va.y + f2*vb.y;
  r.z = f1*va.z + f2*vb.z;
  r.w = f1*va.w + f2*vb.w;
  ((float4*)y)[(size_t)t*(CDIM/4) + q] = r;
}

extern "C" void kernel_launch(void* const* d_in, const int* in_sizes, int n_in,
                              void* d_out, int out_size, void* d_ws, size_t ws_size,
                              hipStream_t stream) {
  const float* x  = (const float*)d_in[0];
  const float* Wr = (const float*)d_in[1];
  const float* Wg = (const float*)d_in[2];
  const float* Wu = (const float*)d_in[3];
  const float* Wp = (const float*)d_in[4];
  float* y = (float*)d_out;

  char* p = (char*)d_ws;
  auto alloc = [&](size_t bytes) { char* r = p; p += (bytes + 255) & ~(size_t)255; return r; };
  unsigned short* WguT = (unsigned short*)alloc((size_t)NEXP*2*IDIM*CDIM*2);
  unsigned short* WpT  = (unsigned short*)alloc((size_t)NEXP*CDIM*IDIM*2);
  unsigned short* ein  = (unsigned short*)alloc((size_t)EROWS*CDIM*2);
  unsigned short* h    = (unsigned short*)alloc((size_t)EROWS*IDIM*2);
  float* outbuf = (float*)alloc((size_t)EROWS*CDIM*4);
  float* probs  = (float*)alloc((size_t)NTOK*NEXP*4);
  int* idx1 = (int*)alloc(NTOK*4);
  int* idx2 = (int*)alloc(NTOK*4);
  int* c1   = (int*)alloc(NTOK*4);
  int* c2   = (int*)alloc(NTOK*4);
  float* g1r = (float*)alloc(NTOK*4);
  float* g2r = (float*)alloc(NTOK*4);
  float* g1o = (float*)alloc(NTOK*4);
  float* g2o = (float*)alloc(NTOK*4);
  int* bufmap = (int*)alloc(EROWS*4);

  size_t required = (size_t)(p - (char*)d_ws);
  if (ws_size < required) return;

  hipMemsetAsync(bufmap, 0xFF, EROWS*sizeof(int), stream);

  wgu_cvt64<<<2*NEXP*(CDIM/64)*(IDIM/64), 256, 0, stream>>>(Wg, Wu, WguT);
  transpose_cvt64<<<NEXP*(IDIM/64)*(CDIM/64), 256, 0, stream>>>(Wp, WpT, IDIM, CDIM);

  router_kernel<<<NTOK/4, 256, 0, stream>>>(x, Wr, probs, idx1, idx2, g1r, g2r);
  scan_kernel<<<1, 1024, 0, stream>>>(idx1, idx2, g1r, g2r, probs, bufmap,
                                      c1, c2, g1o, g2o, y + (size_t)NTOK*CDIM);
  dispatch_kernel<<<EROWS, 192, 0, stream>>>(x, bufmap, ein);

  gemm1_8ph<CDIM><<<NEXP*5*(2*IDIM/256), 512, 0, stream>>>(ein, WguT, h);
  gemm_bt<IDIM, false><<<NEXP*10*(CDIM/128), 256, 0, stream>>>(
      h, WpT, outbuf, CDIM/128, CDIM);

  combine_kernel<<<NTOK, 192, 0, stream>>>(outbuf, c1, c2, g1o, g2o, y);
}

// Round 5
// 312.800 us; speedup vs baseline: 1.0471x; 1.0128x over previous
//
#include <hip/hip_runtime.h>
#include <cstdint>
#include <cstddef>

#define NTOK 8192
#define NEXP 8
#define CAP 1280
#define CDIM 768
#define IDIM 3072
#define EROWS (NEXP*CAP)   /* 10240 */

typedef __attribute__((ext_vector_type(8))) short short8;
typedef __attribute__((ext_vector_type(4))) float f32x4;
typedef __attribute__((ext_vector_type(4))) unsigned short us4;
typedef __attribute__((ext_vector_type(8))) unsigned short us8;

__device__ __forceinline__ unsigned short f2b(float f) {
  unsigned u = __builtin_bit_cast(unsigned, f);
  u += 0x7FFFu + ((u >> 16) & 1u);          // round-to-nearest-even
  return (unsigned short)(u >> 16);
}
__device__ __forceinline__ float b2f(unsigned short u) {
  return __builtin_bit_cast(float, ((unsigned)u) << 16);
}

// ---------------- 64x64 vectorized transpose + f32->bf16 (Wp) ----------------
__global__ __launch_bounds__(256) void transpose_cvt64(const float* __restrict__ src,
    unsigned short* __restrict__ dst, int R, int S) {
  int tilesS = S >> 6, tilesR = R >> 6;
  int perE = tilesR * tilesS;
  int e = blockIdx.x / perE;
  int rem = blockIdx.x % perE;
  int rt = rem / tilesS, st = rem % tilesS;
  const float* se = src + (size_t)e*R*S + ((size_t)rt*64)*S + st*64;
  unsigned short* de = dst + (size_t)e*R*S + ((size_t)st*64)*R + rt*64;
  __shared__ float tile[64][65];
  int c4 = (threadIdx.x & 15)*4, rr = threadIdx.x >> 4;   // rr 0..15
#pragma unroll
  for (int p = 0; p < 4; ++p) {
    float4 v = *(const float4*)(se + (size_t)(rr + 16*p)*S + c4);
    tile[rr + 16*p][c4+0] = v.x; tile[rr + 16*p][c4+1] = v.y;
    tile[rr + 16*p][c4+2] = v.z; tile[rr + 16*p][c4+3] = v.w;
  }
  __syncthreads();
#pragma unroll
  for (int p = 0; p < 4; ++p) {
    int s = rr + 16*p;
    us4 o;
    o.x = f2b(tile[c4+0][s]); o.y = f2b(tile[c4+1][s]);
    o.z = f2b(tile[c4+2][s]); o.w = f2b(tile[c4+3][s]);
    *(us4*)(de + (size_t)s*R + c4) = o;
  }
}

// ---------------- Wg+Wu -> interleaved-transposed combined Wgu (64x64) -------
__global__ __launch_bounds__(256) void wgu_cvt64(const float* __restrict__ Wg,
    const float* __restrict__ Wu, unsigned short* __restrict__ Wgu) {
  const int tilesR = CDIM/64, tilesS = IDIM/64;    // 12, 48
  const int perE = tilesR * tilesS;
  int sel = blockIdx.x / (NEXP*perE);
  int rem = blockIdx.x % (NEXP*perE);
  int e = rem / perE; int r2 = rem % perE;
  int rt = r2 / tilesS, st = r2 % tilesS;
  const float* se = (sel ? Wu : Wg) + (size_t)e*CDIM*IDIM + ((size_t)rt*64)*IDIM + st*64;
  __shared__ float tile[64][65];
  int c4 = (threadIdx.x & 15)*4, rr = threadIdx.x >> 4;
#pragma unroll
  for (int p = 0; p < 4; ++p) {
    float4 v = *(const float4*)(se + (size_t)(rr + 16*p)*IDIM + c4);
    tile[rr + 16*p][c4+0] = v.x; tile[rr + 16*p][c4+1] = v.y;
    tile[rr + 16*p][c4+2] = v.z; tile[rr + 16*p][c4+3] = v.w;
  }
  __syncthreads();
  unsigned short* dstE = Wgu + (size_t)e*(2*IDIM)*CDIM;
#pragma unroll
  for (int p = 0; p < 4; ++p) {
    int s = rr + 16*p;
    int np = 128*st + 32*(s>>4) + (s&15) + sel*16;
    us4 o;
    o.x = f2b(tile[c4+0][s]); o.y = f2b(tile[c4+1][s]);
    o.z = f2b(tile[c4+2][s]); o.w = f2b(tile[c4+3][s]);
    *(us4*)(dstE + (size_t)np*CDIM + rt*64 + c4) = o;
  }
}

// ---------------- router ----------------
__global__ __launch_bounds__(256) void router_kernel(const float* __restrict__ x,
    const float* __restrict__ Wr, float* __restrict__ probs,
    int* __restrict__ idx1, int* __restrict__ idx2,
    float* __restrict__ g1r, float* __restrict__ g2r) {
  __shared__ float WrT[NEXP*CDIM];
  for (int i = threadIdx.x; i < NEXP*CDIM; i += 256) {
    int c = i >> 3, e = i & 7;
    WrT[e*CDIM + c] = Wr[i];
  }
  __syncthreads();
  int w = threadIdx.x >> 6, l = threadIdx.x & 63;
  int t = blockIdx.x*4 + w;
  float acc[NEXP];
#pragma unroll
  for (int e = 0; e < NEXP; ++e) acc[e] = 0.f;
  for (int k = 0; k < CDIM/64; ++k) {
    float xv = x[(size_t)t*CDIM + k*64 + l];
#pragma unroll
    for (int e = 0; e < NEXP; ++e) acc[e] += xv * WrT[e*CDIM + k*64 + l];
  }
#pragma unroll
  for (int off = 32; off > 0; off >>= 1) {
#pragma unroll
    for (int e = 0; e < NEXP; ++e) acc[e] += __shfl_xor(acc[e], off);
  }
  if (l == 0) {
    float m = acc[0];
#pragma unroll
    for (int e = 1; e < NEXP; ++e) m = fmaxf(m, acc[e]);
    float p[NEXP]; float s = 0.f;
#pragma unroll
    for (int e = 0; e < NEXP; ++e) { p[e] = expf(acc[e] - m); s += p[e]; }
    float inv = 1.f / s;
#pragma unroll
    for (int e = 0; e < NEXP; ++e) { p[e] *= inv; probs[(size_t)t*NEXP + e] = p[e]; }
    int i1 = 0; float b1 = p[0];
#pragma unroll
    for (int e = 1; e < NEXP; ++e) if (p[e] > b1) { b1 = p[e]; i1 = e; }
    int i2 = -1; float b2 = -1e30f;
#pragma unroll
    for (int e = 0; e < NEXP; ++e) if (e != i1 && p[e] > b2) { b2 = p[e]; i2 = e; }
    float gs = fmaxf(b1 + b2, 1e-9f);
    g1r[t] = b1 / gs; g2r[t] = b2 / gs;
    idx1[t] = i1; idx2[t] = i2;
  }
}

// ---------------- scan ----------------
__global__ __launch_bounds__(1024) void scan_kernel(
    const int* __restrict__ idx1, const int* __restrict__ idx2,
    const float* __restrict__ g1r, const float* __restrict__ g2r,
    const float* __restrict__ probs,
    int* __restrict__ bufmap,
    int* __restrict__ c1o, int* __restrict__ c2o,
    float* __restrict__ g1o, float* __restrict__ g2o,
    float* __restrict__ aux_out) {
  __shared__ unsigned int scanbuf[1024][9];
  __shared__ unsigned int totals[NEXP];
  int tid = threadIdx.x;
  int e1[8], e2[8];
  unsigned int cnt[NEXP];
#pragma unroll
  for (int k = 0; k < NEXP; ++k) cnt[k] = 0;
  for (int j = 0; j < 8; ++j) {
    int t = tid*8 + j;
    e1[j] = idx1[t]; e2[j] = idx2[t];
    cnt[e1[j]] += 1u;
    cnt[e2[j]] += (1u << 16);
  }
#pragma unroll
  for (int k = 0; k < NEXP; ++k) scanbuf[tid][k] = cnt[k];
  unsigned int run[NEXP];
#pragma unroll
  for (int k = 0; k < NEXP; ++k) run[k] = cnt[k];
  __syncthreads();
  for (int off = 1; off < 1024; off <<= 1) {
    unsigned int add[NEXP];
#pragma unroll
    for (int k = 0; k < NEXP; ++k) add[k] = 0;
    if (tid >= off) {
#pragma unroll
      for (int k = 0; k < NEXP; ++k) add[k] = scanbuf[tid - off][k];
    }
    __syncthreads();
#pragma unroll
    for (int k = 0; k < NEXP; ++k) { run[k] += add[k]; scanbuf[tid][k] = run[k]; }
    __syncthreads();
  }
  if (tid == 1023) {
#pragma unroll
    for (int k = 0; k < NEXP; ++k) totals[k] = run[k];
  }
  __syncthreads();
  unsigned int excl[NEXP];
#pragma unroll
  for (int k = 0; k < NEXP; ++k) excl[k] = run[k] - cnt[k];
  int cnt1c[NEXP];
#pragma unroll
  for (int k = 0; k < NEXP; ++k) cnt1c[k] = min((int)(totals[k] & 0xFFFFu), CAP);

  for (int j = 0; j < 8; ++j) {
    int t = tid*8 + j;
    int a = e1[j];
    int pos1 = (int)(excl[a] & 0xFFFFu); excl[a] += 1u;
    int slot1 = a*CAP + pos1;
    bool m1 = pos1 < CAP;
    if (m1) bufmap[slot1] = t;
    int b = e2[j];
    int pos2 = (int)(excl[b] >> 16) + cnt1c[b]; excl[b] += (1u << 16);
    int slot2 = b*CAP + pos2;
    bool m2 = pos2 < CAP;
    if (m2) bufmap[slot2] = t;
    float G1 = m1 ? g1r[t] : 0.f;
    float G2 = m2 ? g2r[t] : 0.f;
    float den = fmaxf(G1 + G2, 1e-9f);
    g1o[t] = G1 / den; g2o[t] = G2 / den;
    c1o[t] = min(slot1, EROWS - 1);
    c2o[t] = min(slot2, EROWS - 1);
  }

  float imp[NEXP];
#pragma unroll
  for (int k = 0; k < NEXP; ++k) imp[k] = 0.f;
  for (int j = 0; j < 8; ++j) {
    int t = tid*8 + j;
    const float4* pr = (const float4*)(probs + (size_t)t*NEXP);
    float4 a0 = pr[0], a1 = pr[1];
    imp[0] += a0.x; imp[1] += a0.y; imp[2] += a0.z; imp[3] += a0.w;
    imp[4] += a1.x; imp[5] += a1.y; imp[6] += a1.z; imp[7] += a1.w;
  }
  __syncthreads();
  float* fbuf = (float*)&scanbuf[0][0];
#pragma unroll
  for (int k = 0; k < NEXP; ++k) fbuf[tid*9 + k] = imp[k];
  __syncthreads();
  for (int s = 512; s >= 1; s >>= 1) {
    if (tid < s) {
#pragma unroll
      for (int k = 0; k < NEXP; ++k) fbuf[tid*9 + k] += fbuf[(tid + s)*9 + k];
    }
    __syncthreads();
  }
  if (tid == 0) {
    float aux = 0.f;
#pragma unroll
    for (int k = 0; k < NEXP; ++k) {
      float importance = fbuf[k] / (float)NTOK;
      float loadk = (float)((totals[k] & 0xFFFFu) + (totals[k] >> 16)) / ((float)NTOK * 2.0f);
      aux += importance * loadk;
    }
    aux_out[0] = aux * (float)NEXP * 0.01f;
  }
}

// ---------------- dispatch ----------------
__global__ __launch_bounds__(192) void dispatch_kernel(const float* __restrict__ x,
    const int* __restrict__ bufmap, unsigned short* __restrict__ ein) {
  int r = blockIdx.x;
  int t = bufmap[r];
  int q = threadIdx.x;
  float4 v = make_float4(0.f, 0.f, 0.f, 0.f);
  if (t >= 0) v = ((const float4*)x)[(size_t)t*(CDIM/4) + q];
  us4 o;
  o.x = f2b(v.x); o.y = f2b(v.y); o.z = f2b(v.z); o.w = f2b(v.w);
  ((us4*)ein)[(size_t)r*(CDIM/4) + q] = o;
}

// =============== GEMM1: 256x256 8-phase, A x2 / B x3 LDS buffers (160 KiB) ====
// Sync rule (m152/round-4 lesson): every VMW sits BEFORE the barrier that
// precedes the dependent cross-wave LDS reads: wave drains own loads -> BAR
// proves all waves drained -> reads safe.
#define BAR  asm volatile("s_barrier" ::: "memory")
#define VMW(N) asm volatile("s_waitcnt vmcnt(" #N ")" ::: "memory")
#define P1 __builtin_amdgcn_s_setprio(1)
#define P0 __builtin_amdgcn_s_setprio(0)

template<int KD>
__global__ __launch_bounds__(512, 2) void gemm1_8ph(
    const unsigned short* __restrict__ A,
    const unsigned short* __restrict__ Bw,
    unsigned short* __restrict__ H) {
  constexpr int NT = KD/64;        // 12
  constexpr int NITER = NT/2;      // 6
  // 160 KiB: A0 @0, A1 @16384, B bufs @32768/49152/65536 (ushort units)
  __shared__ unsigned short lds[81920];

  const int bid = blockIdx.x;
  const int chunk = gridDim.x >> 3;              // 120 = one expert per XCD
  const int tile = (bid & 7)*chunk + (bid >> 3);
  const int e = tile / 120;
  const int rem = tile % 120;
  const int nt = rem / 5, mt = rem % 5;

  const int tid = threadIdx.x;
  const int l = tid & 63, wid = tid >> 6;
  const int wr = wid >> 2, wc = wid & 3;
  const int lrow = l & 15, khi = l >> 4;

  const unsigned short* Ab = A  + (size_t)e*CAP*KD      + (size_t)mt*256*KD;
  const unsigned short* Bb = Bw + (size_t)e*(2*IDIM)*KD + (size_t)nt*256*KD;

  // staging: linear LDS dest, inverse-swizzled global source
  const int srow = tid >> 3;
  const int scol = (tid & 7) ^ (srow & 7);
  const size_t lane_off = (size_t)srow*KD + scol*8;
  const int lds_st = wid*512;

#define STG(dstu, srcp, half, kt) do { \
    const unsigned short* s_ = (srcp) + lane_off + (size_t)(half)*128*KD + (size_t)(kt)*64; \
    unsigned short* d_ = (unsigned short*)lds + (dstu) + (half)*8192 + lds_st; \
    __builtin_amdgcn_global_load_lds((const __attribute__((address_space(1))) void*)s_, \
        (__attribute__((address_space(3))) void*)d_, 16, 0, 0); \
    __builtin_amdgcn_global_load_lds((const __attribute__((address_space(1))) void*)(s_ + (size_t)64*KD), \
        (__attribute__((address_space(3))) void*)(d_ + 4096), 16, 0, 0); \
  } while(0)

  const int swz0 = ((khi    ) ^ (lrow & 7)) * 8;
  const int swz1 = ((4 + khi) ^ (lrow & 7)) * 8;
  const int aoff = wr*8192 + lrow*64;                      // within A buf
  const int boff = (wc>>1)*8192 + ((wc&1)*64 + lrow)*64;   // within B buf

#define LDA(ab, dst, mb) do { _Pragma("unroll") for (int m_=0;m_<4;++m_) { \
    dst[m_][0] = *(const short8*)(lds + (ab) + aoff + ((mb)+m_)*1024 + swz0); \
    dst[m_][1] = *(const short8*)(lds + (ab) + aoff + ((mb)+m_)*1024 + swz1); } } while(0)
#define LDB(bb, dst, nb) do { _Pragma("unroll") for (int n_=0;n_<2;++n_) { \
    dst[n_][0] = *(const short8*)(lds + (bb) + boff + ((nb)+n_)*1024 + swz0); \
    dst[n_][1] = *(const short8*)(lds + (bb) + boff + ((nb)+n_)*1024 + swz1); } } while(0)
#define QUAD(af, bf, mb, nb) do { _Pragma("unroll") for (int r_=0;r_<2;++r_) \
    _Pragma("unroll") for (int n_=0;n_<2;++n_) \
    _Pragma("unroll") for (int m_=0;m_<4;++m_) \
      acc[(mb)+m_][(nb)+n_] = __builtin_amdgcn_mfma_f32_16x16x32_bf16(af[m_][r_], bf[n_][r_], acc[(mb)+m_][(nb)+n_], 0,0,0); } while(0)

  f32x4 acc[8][4];
#pragma unroll
  for (int i = 0; i < 8; ++i)
#pragma unroll
    for (int j = 0; j < 4; ++j) acc[i][j] = (f32x4){0.f,0.f,0.f,0.f};

  short8 a[4][2], bl[2][2], bh[2][2];

  int bA_ = 32768, bB_ = 49152, bC_ = 65536;

  // prologue: tile0 {A,B} first (so VMW(8) retires exactly tile0), then tile1
  STG(0, Ab, 0, 0);      STG(bA_, Bb, 0, 0);
  STG(0, Ab, 1, 0);      STG(bA_, Bb, 1, 0);
  STG(16384, Ab, 0, 1);  STG(bB_, Bb, 0, 1);
  STG(16384, Ab, 1, 1);  STG(bB_, Bb, 1, 1);
  VMW(8);   // tile0 landed (8 loads of tile1 may remain in flight)
  BAR;

  // ITER computes tiles t (A0,bA_) and t+1 (A1,bB_); stages:
  //  ph1/2: B(t+2)->bC_, ph4/5: A(t+2)->A0, ph5/6: B(t+3)->bA_, ph8: A(t+3)->A1
  // VM4 (=VMW(6)) in ph4 slot BEFORE its BAR: retires tile t+1 (8 entering +
  //   6 issued this iter = 14 -> drain to 6). Guards ph5 reads.
  // VM8 (=VMW(8)) in ph8 slot BEFORE its BAR: retires tile t+2 (16 -> 8).
  //   Guards next ITER's ph1 reads.
#define ITER(t2, t3, DOS, VM4, VM8) \
    LDA(0, a, 0); LDB(bA_, bl, 0); if (DOS) STG(bC_, Bb, 0, (t2)); \
    BAR; P1; QUAD(a, bl, 0, 0); P0; BAR; \
    LDB(bA_, bh, 2); if (DOS) STG(bC_, Bb, 1, (t2)); \
    BAR; P1; QUAD(a, bh, 0, 2); P0; BAR; \
    LDA(0, a, 4); \
    BAR; P1; QUAD(a, bh, 4, 2); P0; BAR; \
    if (DOS) STG(0, Ab, 0, (t2)); VM4; \
    BAR; P1; QUAD(a, bl, 4, 0); P0; BAR; \
    LDA(16384, a, 0); LDB(bB_, bl, 0); if (DOS) { STG(0, Ab, 1, (t2)); STG(bA_, Bb, 0, (t3)); } \
    BAR; P1; QUAD(a, bl, 0, 0); P0; BAR; \
    LDB(bB_, bh, 2); if (DOS) STG(bA_, Bb, 1, (t3)); \
    BAR; P1; QUAD(a, bh, 0, 2); P0; BAR; \
    LDA(16384, a, 4); \
    BAR; P1; QUAD(a, bh, 4, 2); P0; BAR; \
    if (DOS) { STG(16384, Ab, 0, (t3)); STG(16384, Ab, 1, (t3)); } VM8; \
    BAR; P1; QUAD(a, bl, 4, 0); P0; BAR;

#pragma unroll 1
  for (int i = 0; i < NITER-1; ++i) {
    const int t2 = 2*i+2, t3 = 2*i+3;
    ITER(t2, t3, true, VMW(6), VMW(8));
    int tmp = bC_; bC_ = bB_; bB_ = bA_; bA_ = tmp;
  }
  // tail: no stages; VMW(0) in ph4 slot drains tile NT-1 before ph5 reads.
  ITER(0, 0, false, VMW(0), VMW(0));

#undef ITER
#undef QUAD
#undef LDB
#undef LDA
#undef STG

  // ---- epilogue: silu(g)*u -> LDS (stride 136) -> coalesced us8 stores ----
  __syncthreads();
  {
    const int cb0 = wc*32 + lrow;
    const int rb0 = wr*128 + khi*4;
#pragma unroll
    for (int m = 0; m < 8; ++m)
#pragma unroll
      for (int p = 0; p < 2; ++p) {
        f32x4 g = acc[m][2*p], u = acc[m][2*p+1];
#pragma unroll
        for (int r = 0; r < 4; ++r) {
          float gv = g[r];
          float hv = gv / (1.f + __expf(-gv)) * u[r];
          lds[(rb0 + m*16 + r)*136 + cb0 + p*16] = f2b(hv);
        }
      }
  }
  __syncthreads();
  const size_t rowg = (size_t)e*CAP + (size_t)mt*256;
  const size_t colg = (size_t)nt*128 + (size_t)(l & 15)*8;
#pragma unroll
  for (int i = 0; i < 8; ++i) {
    int row = wid*32 + i*4 + (l >> 4);
    us8 v = *(const us8*)(lds + row*136 + (l & 15)*8);
    *(us8*)(H + (rowg + row)*(size_t)IDIM + colg) = v;
  }
}

// ---------------- GEMM2: m97-style 128x128, bf16 out via LDS coalesce --------
template<int K>
__global__ __launch_bounds__(256, 2) void gemm_bt(
    const unsigned short* __restrict__ A,
    const unsigned short* __restrict__ B0,
    unsigned short* __restrict__ Fout,
    int Ntiles, int N) {
  constexpr int MT = 10;
  int chunk = gridDim.x >> 3;
  int bid = blockIdx.x;
  int tile = (bid & 7)*chunk + (bid >> 3);
  int perE = MT * Ntiles;
  int e = tile / perE, rem = tile % perE;
  int mt = rem / Ntiles, nt = rem % Ntiles;

  const unsigned short* Ae  = A  + (size_t)e*CAP*K + (size_t)mt*128*K;
  const unsigned short* B0e = B0 + (size_t)e*N*K   + (size_t)nt*128*K;

  __shared__ unsigned short sh[16384];   // Alds @0, Blds @8192
  unsigned short* Alds = sh;
  unsigned short* B0lds = sh + 8192;

  int tid = threadIdx.x;
  int l = tid & 63, w = tid >> 6;
  int rbase = w*8 + (l >> 3);
  int csrc  = (l & 7) ^ ((l >> 3) & 7);
  size_t gbase = (size_t)rbase*K + (size_t)csrc*8;
  int ldsoff = w*512;

  f32x4 acc0[16];
#pragma unroll
  for (int i = 0; i < 16; ++i) acc0[i] = (f32x4){0.f,0.f,0.f,0.f};

  int wm = (w >> 1)*64, wn = (w & 1)*64;
  int lrow = l & 15, khi = l >> 4;

  for (int kt = 0; kt < K/64; ++kt) {
    const unsigned short* Ag  = Ae  + gbase + (size_t)kt*64;
    const unsigned short* Bg0 = B0e + gbase + (size_t)kt*64;
#pragma unroll
    for (int q = 0; q < 4; ++q) {
      __builtin_amdgcn_global_load_lds(
          (const __attribute__((address_space(1))) void*)(Ag + (size_t)q*32*K),
          (__attribute__((address_space(3))) void*)(Alds + ldsoff + q*2048), 16, 0, 0);
    }
#pragma unroll
    for (int q = 0; q < 4; ++q) {
      __builtin_amdgcn_global_load_lds(
          (const __attribute__((address_space(1))) void*)(Bg0 + (size_t)q*32*K),
          (__attribute__((address_space(3))) void*)(B0lds + ldsoff + q*2048), 16, 0, 0);
    }
    __syncthreads();
#pragma unroll
    for (int kk = 0; kk < 2; ++kk) {
      int cs = (kk*4 + khi) ^ (l & 7);
      short8 af[4];
#pragma unroll
      for (int m = 0; m < 4; ++m) {
        int row = wm + m*16 + lrow;
        af[m] = *(const short8*)(Alds + row*64 + cs*8);
      }
#pragma unroll
      for (int n = 0; n < 4; ++n) {
        int rowb = wn + n*16 + lrow;
        short8 b0 = *(const short8*)(B0lds + rowb*64 + cs*8);
#pragma unroll
        for (int m = 0; m < 4; ++m)
          acc0[m*4+n] = __builtin_amdgcn_mfma_f32_16x16x32_bf16(af[m], b0, acc0[m*4+n], 0, 0, 0);
      }
    }
    __syncthreads();
  }

  // bf16 epilogue via LDS, two 64-row rounds (stride 136 us, 16B-aligned)
  const size_t rowg = (size_t)e*CAP + (size_t)mt*128;
  const size_t colg = (size_t)nt*128;
#pragma unroll
  for (int h = 0; h < 2; ++h) {
    if ((w >> 1) == h) {
#pragma unroll
      for (int m = 0; m < 4; ++m)
#pragma unroll
        for (int n = 0; n < 4; ++n) {
          f32x4 v = acc0[m*4+n];
#pragma unroll
          for (int r = 0; r < 4; ++r)
            sh[(m*16 + khi*4 + r)*136 + wn + n*16 + lrow] = f2b(v[r]);
        }
    }
    __syncthreads();
#pragma unroll
    for (int jj = 0; jj < 4; ++jj) {
      int idx = tid + 256*jj;            // 0..1023
      int rp = idx >> 4, ch = idx & 15;
      us8 v = *(const us8*)(sh + rp*136 + ch*8);
      *(us8*)(Fout + (rowg + h*64 + rp)*(size_t)N + colg + ch*8) = v;
    }
    __syncthreads();
  }
}

// ---------------- combine (bf16 expert outputs -> f32 y) ----------------
__global__ __launch_bounds__(192) void combine_kernel(const unsigned short* __restrict__ outbuf,
    const int* __restrict__ c1, const int* __restrict__ c2,
    const float* __restrict__ g1, const float* __restrict__ g2,
    float* __restrict__ y) {
  int t = blockIdx.x;
  int q = threadIdx.x;
  float f1 = g1[t], f2 = g2[t];
  int a = c1[t], b = c2[t];
  us4 va = ((const us4*)outbuf)[(size_t)a*(CDIM/4) + q];
  us4 vb = ((const us4*)outbuf)[(size_t)b*(CDIM/4) + q];
  float4 r;
  r.x = f1*b2f(va.x) + f2*b2f(vb.x);
  r.y = f1*b2f(va.y) + f2*b2f(vb.y);
  r.z = f1*b2f(va.z) + f2*b2f(vb.z);
  r.w = f1*b2f(va.w) + f2*b2f(vb.w);
  ((float4*)y)[(size_t)t*(CDIM/4) + q] = r;
}

extern "C" void kernel_launch(void* const* d_in, const int* in_sizes, int n_in,
                              void* d_out, int out_size, void* d_ws, size_t ws_size,
                              hipStream_t stream) {
  const float* x  = (const float*)d_in[0];
  const float* Wr = (const float*)d_in[1];
  const float* Wg = (const float*)d_in[2];
  const float* Wu = (const float*)d_in[3];
  const float* Wp = (const float*)d_in[4];
  float* y = (float*)d_out;

  char* p = (char*)d_ws;
  auto alloc = [&](size_t bytes) { char* r = p; p += (bytes + 255) & ~(size_t)255; return r; };
  unsigned short* WguT = (unsigned short*)alloc((size_t)NEXP*2*IDIM*CDIM*2);
  unsigned short* WpT  = (unsigned short*)alloc((size_t)NEXP*CDIM*IDIM*2);
  unsigned short* ein  = (unsigned short*)alloc((size_t)EROWS*CDIM*2);
  unsigned short* h    = (unsigned short*)alloc((size_t)EROWS*IDIM*2);
  unsigned short* outbuf = (unsigned short*)alloc((size_t)EROWS*CDIM*2);
  float* probs  = (float*)alloc((size_t)NTOK*NEXP*4);
  int* idx1 = (int*)alloc(NTOK*4);
  int* idx2 = (int*)alloc(NTOK*4);
  int* c1   = (int*)alloc(NTOK*4);
  int* c2   = (int*)alloc(NTOK*4);
  float* g1r = (float*)alloc(NTOK*4);
  float* g2r = (float*)alloc(NTOK*4);
  float* g1o = (float*)alloc(NTOK*4);
  float* g2o = (float*)alloc(NTOK*4);
  int* bufmap = (int*)alloc(EROWS*4);

  size_t required = (size_t)(p - (char*)d_ws);
  if (ws_size < required) return;

  hipMemsetAsync(bufmap, 0xFF, EROWS*sizeof(int), stream);

  wgu_cvt64<<<2*NEXP*(CDIM/64)*(IDIM/64), 256, 0, stream>>>(Wg, Wu, WguT);
  transpose_cvt64<<<NEXP*(IDIM/64)*(CDIM/64), 256, 0, stream>>>(Wp, WpT, IDIM, CDIM);

  router_kernel<<<NTOK/4, 256, 0, stream>>>(x, Wr, probs, idx1, idx2, g1r, g2r);
  scan_kernel<<<1, 1024, 0, stream>>>(idx1, idx2, g1r, g2r, probs, bufmap,
                                      c1, c2, g1o, g2o, y + (size_t)NTOK*CDIM);
  dispatch_kernel<<<EROWS, 192, 0, stream>>>(x, bufmap, ein);

  gemm1_8ph<CDIM><<<NEXP*5*(2*IDIM/256), 512, 0, stream>>>(ein, WguT, h);
  gemm_bt<IDIM><<<NEXP*10*(CDIM/128), 256, 0, stream>>>(
      h, WpT, outbuf, CDIM/128, CDIM);

  combine_kernel<<<NTOK, 192, 0, stream>>>(outbuf, c1, c2, g1o, g2o, y);
}

// Round 6
// 295.160 us; speedup vs baseline: 1.1096x; 1.0598x over previous
//
#include <hip/hip_runtime.h>
#include <cstdint>
#include <cstddef>

#define NTOK 8192
#define NEXP 8
#define CAP 1280
#define CDIM 768
#define IDIM 3072
#define EROWS (NEXP*CAP)   /* 10240 */

typedef __attribute__((ext_vector_type(8))) short short8;
typedef __attribute__((ext_vector_type(4))) float f32x4;
typedef __attribute__((ext_vector_type(4))) unsigned short us4;
typedef __attribute__((ext_vector_type(8))) unsigned short us8;

__device__ __forceinline__ unsigned short f2b(float f) {
  unsigned u = __builtin_bit_cast(unsigned, f);
  u += 0x7FFFu + ((u >> 16) & 1u);          // round-to-nearest-even
  return (unsigned short)(u >> 16);
}
__device__ __forceinline__ float b2f(unsigned short u) {
  return __builtin_bit_cast(float, ((unsigned)u) << 16);
}

// ---------------- 64x64 vectorized transpose + f32->bf16 (Wp) ----------------
__global__ __launch_bounds__(256) void transpose_cvt64(const float* __restrict__ src,
    unsigned short* __restrict__ dst, int R, int S) {
  int tilesS = S >> 6, tilesR = R >> 6;
  int perE = tilesR * tilesS;
  int e = blockIdx.x / perE;
  int rem = blockIdx.x % perE;
  int rt = rem / tilesS, st = rem % tilesS;
  const float* se = src + (size_t)e*R*S + ((size_t)rt*64)*S + st*64;
  unsigned short* de = dst + (size_t)e*R*S + ((size_t)st*64)*R + rt*64;
  __shared__ float tile[64][65];
  int c4 = (threadIdx.x & 15)*4, rr = threadIdx.x >> 4;   // rr 0..15
#pragma unroll
  for (int p = 0; p < 4; ++p) {
    float4 v = *(const float4*)(se + (size_t)(rr + 16*p)*S + c4);
    tile[rr + 16*p][c4+0] = v.x; tile[rr + 16*p][c4+1] = v.y;
    tile[rr + 16*p][c4+2] = v.z; tile[rr + 16*p][c4+3] = v.w;
  }
  __syncthreads();
#pragma unroll
  for (int p = 0; p < 4; ++p) {
    int s = rr + 16*p;
    us4 o;
    o.x = f2b(tile[c4+0][s]); o.y = f2b(tile[c4+1][s]);
    o.z = f2b(tile[c4+2][s]); o.w = f2b(tile[c4+3][s]);
    *(us4*)(de + (size_t)s*R + c4) = o;
  }
}

// ---------------- Wg+Wu -> interleaved-transposed combined Wgu (64x64) -------
__global__ __launch_bounds__(256) void wgu_cvt64(const float* __restrict__ Wg,
    const float* __restrict__ Wu, unsigned short* __restrict__ Wgu) {
  const int tilesR = CDIM/64, tilesS = IDIM/64;    // 12, 48
  const int perE = tilesR * tilesS;
  int sel = blockIdx.x / (NEXP*perE);
  int rem = blockIdx.x % (NEXP*perE);
  int e = rem / perE; int r2 = rem % perE;
  int rt = r2 / tilesS, st = r2 % tilesS;
  const float* se = (sel ? Wu : Wg) + (size_t)e*CDIM*IDIM + ((size_t)rt*64)*IDIM + st*64;
  __shared__ float tile[64][65];
  int c4 = (threadIdx.x & 15)*4, rr = threadIdx.x >> 4;
#pragma unroll
  for (int p = 0; p < 4; ++p) {
    float4 v = *(const float4*)(se + (size_t)(rr + 16*p)*IDIM + c4);
    tile[rr + 16*p][c4+0] = v.x; tile[rr + 16*p][c4+1] = v.y;
    tile[rr + 16*p][c4+2] = v.z; tile[rr + 16*p][c4+3] = v.w;
  }
  __syncthreads();
  unsigned short* dstE = Wgu + (size_t)e*(2*IDIM)*CDIM;
#pragma unroll
  for (int p = 0; p < 4; ++p) {
    int s = rr + 16*p;
    int np = 128*st + 32*(s>>4) + (s&15) + sel*16;
    us4 o;
    o.x = f2b(tile[c4+0][s]); o.y = f2b(tile[c4+1][s]);
    o.z = f2b(tile[c4+2][s]); o.w = f2b(tile[c4+3][s]);
    *(us4*)(dstE + (size_t)np*CDIM + rt*64 + c4) = o;
  }
}

// ---------------- router ----------------
__global__ __launch_bounds__(256) void router_kernel(const float* __restrict__ x,
    const float* __restrict__ Wr, float* __restrict__ probs,
    int* __restrict__ idx1, int* __restrict__ idx2,
    float* __restrict__ g1r, float* __restrict__ g2r) {
  __shared__ float WrT[NEXP*CDIM];
  for (int i = threadIdx.x; i < NEXP*CDIM; i += 256) {
    int c = i >> 3, e = i & 7;
    WrT[e*CDIM + c] = Wr[i];
  }
  __syncthreads();
  int w = threadIdx.x >> 6, l = threadIdx.x & 63;
  int t = blockIdx.x*4 + w;
  float acc[NEXP];
#pragma unroll
  for (int e = 0; e < NEXP; ++e) acc[e] = 0.f;
  for (int k = 0; k < CDIM/64; ++k) {
    float xv = x[(size_t)t*CDIM + k*64 + l];
#pragma unroll
    for (int e = 0; e < NEXP; ++e) acc[e] += xv * WrT[e*CDIM + k*64 + l];
  }
#pragma unroll
  for (int off = 32; off > 0; off >>= 1) {
#pragma unroll
    for (int e = 0; e < NEXP; ++e) acc[e] += __shfl_xor(acc[e], off);
  }
  if (l == 0) {
    float m = acc[0];
#pragma unroll
    for (int e = 1; e < NEXP; ++e) m = fmaxf(m, acc[e]);
    float p[NEXP]; float s = 0.f;
#pragma unroll
    for (int e = 0; e < NEXP; ++e) { p[e] = expf(acc[e] - m); s += p[e]; }
    float inv = 1.f / s;
#pragma unroll
    for (int e = 0; e < NEXP; ++e) { p[e] *= inv; probs[(size_t)t*NEXP + e] = p[e]; }
    int i1 = 0; float b1 = p[0];
#pragma unroll
    for (int e = 1; e < NEXP; ++e) if (p[e] > b1) { b1 = p[e]; i1 = e; }
    int i2 = -1; float b2 = -1e30f;
#pragma unroll
    for (int e = 0; e < NEXP; ++e) if (e != i1 && p[e] > b2) { b2 = p[e]; i2 = e; }
    float gs = fmaxf(b1 + b2, 1e-9f);
    g1r[t] = b1 / gs; g2r[t] = b2 / gs;
    idx1[t] = i1; idx2[t] = i2;
  }
}

// ---------------- scan ----------------
__global__ __launch_bounds__(1024) void scan_kernel(
    const int* __restrict__ idx1, const int* __restrict__ idx2,
    const float* __restrict__ g1r, const float* __restrict__ g2r,
    const float* __restrict__ probs,
    int* __restrict__ bufmap,
    int* __restrict__ c1o, int* __restrict__ c2o,
    float* __restrict__ g1o, float* __restrict__ g2o,
    float* __restrict__ aux_out) {
  __shared__ unsigned int scanbuf[1024][9];
  __shared__ unsigned int totals[NEXP];
  int tid = threadIdx.x;
  int e1[8], e2[8];
  unsigned int cnt[NEXP];
#pragma unroll
  for (int k = 0; k < NEXP; ++k) cnt[k] = 0;
  for (int j = 0; j < 8; ++j) {
    int t = tid*8 + j;
    e1[j] = idx1[t]; e2[j] = idx2[t];
    cnt[e1[j]] += 1u;
    cnt[e2[j]] += (1u << 16);
  }
#pragma unroll
  for (int k = 0; k < NEXP; ++k) scanbuf[tid][k] = cnt[k];
  unsigned int run[NEXP];
#pragma unroll
  for (int k = 0; k < NEXP; ++k) run[k] = cnt[k];
  __syncthreads();
  for (int off = 1; off < 1024; off <<= 1) {
    unsigned int add[NEXP];
#pragma unroll
    for (int k = 0; k < NEXP; ++k) add[k] = 0;
    if (tid >= off) {
#pragma unroll
      for (int k = 0; k < NEXP; ++k) add[k] = scanbuf[tid - off][k];
    }
    __syncthreads();
#pragma unroll
    for (int k = 0; k < NEXP; ++k) { run[k] += add[k]; scanbuf[tid][k] = run[k]; }
    __syncthreads();
  }
  if (tid == 1023) {
#pragma unroll
    for (int k = 0; k < NEXP; ++k) totals[k] = run[k];
  }
  __syncthreads();
  unsigned int excl[NEXP];
#pragma unroll
  for (int k = 0; k < NEXP; ++k) excl[k] = run[k] - cnt[k];
  int cnt1c[NEXP];
#pragma unroll
  for (int k = 0; k < NEXP; ++k) cnt1c[k] = min((int)(totals[k] & 0xFFFFu), CAP);

  for (int j = 0; j < 8; ++j) {
    int t = tid*8 + j;
    int a = e1[j];
    int pos1 = (int)(excl[a] & 0xFFFFu); excl[a] += 1u;
    int slot1 = a*CAP + pos1;
    bool m1 = pos1 < CAP;
    if (m1) bufmap[slot1] = t;
    int b = e2[j];
    int pos2 = (int)(excl[b] >> 16) + cnt1c[b]; excl[b] += (1u << 16);
    int slot2 = b*CAP + pos2;
    bool m2 = pos2 < CAP;
    if (m2) bufmap[slot2] = t;
    float G1 = m1 ? g1r[t] : 0.f;
    float G2 = m2 ? g2r[t] : 0.f;
    float den = fmaxf(G1 + G2, 1e-9f);
    g1o[t] = G1 / den; g2o[t] = G2 / den;
    c1o[t] = min(slot1, EROWS - 1);
    c2o[t] = min(slot2, EROWS - 1);
  }

  float imp[NEXP];
#pragma unroll
  for (int k = 0; k < NEXP; ++k) imp[k] = 0.f;
  for (int j = 0; j < 8; ++j) {
    int t = tid*8 + j;
    const float4* pr = (const float4*)(probs + (size_t)t*NEXP);
    float4 a0 = pr[0], a1 = pr[1];
    imp[0] += a0.x; imp[1] += a0.y; imp[2] += a0.z; imp[3] += a0.w;
    imp[4] += a1.x; imp[5] += a1.y; imp[6] += a1.z; imp[7] += a1.w;
  }
  __syncthreads();
  float* fbuf = (float*)&scanbuf[0][0];
#pragma unroll
  for (int k = 0; k < NEXP; ++k) fbuf[tid*9 + k] = imp[k];
  __syncthreads();
  for (int s = 512; s >= 1; s >>= 1) {
    if (tid < s) {
#pragma unroll
      for (int k = 0; k < NEXP; ++k) fbuf[tid*9 + k] += fbuf[(tid + s)*9 + k];
    }
    __syncthreads();
  }
  if (tid == 0) {
    float aux = 0.f;
#pragma unroll
    for (int k = 0; k < NEXP; ++k) {
      float importance = fbuf[k] / (float)NTOK;
      float loadk = (float)((totals[k] & 0xFFFFu) + (totals[k] >> 16)) / ((float)NTOK * 2.0f);
      aux += importance * loadk;
    }
    aux_out[0] = aux * (float)NEXP * 0.01f;
  }
}

// ---------------- dispatch ----------------
__global__ __launch_bounds__(192) void dispatch_kernel(const float* __restrict__ x,
    const int* __restrict__ bufmap, unsigned short* __restrict__ ein) {
  int r = blockIdx.x;
  int t = bufmap[r];
  int q = threadIdx.x;
  float4 v = make_float4(0.f, 0.f, 0.f, 0.f);
  if (t >= 0) v = ((const float4*)x)[(size_t)t*(CDIM/4) + q];
  us4 o;
  o.x = f2b(v.x); o.y = f2b(v.y); o.z = f2b(v.z); o.w = f2b(v.w);
  ((us4*)ein)[(size_t)r*(CDIM/4) + q] = o;
}

// =============== GEMM1: 256x256 8-phase, A x2 / B x3 LDS buffers (160 KiB) ====
// (unchanged from round 5 — verified correct; at m248 grouped-GEMM ceiling)
#define BAR  asm volatile("s_barrier" ::: "memory")
#define VMW(N) asm volatile("s_waitcnt vmcnt(" #N ")" ::: "memory")
#define P1 __builtin_amdgcn_s_setprio(1)
#define P0 __builtin_amdgcn_s_setprio(0)

template<int KD>
__global__ __launch_bounds__(512, 2) void gemm1_8ph(
    const unsigned short* __restrict__ A,
    const unsigned short* __restrict__ Bw,
    unsigned short* __restrict__ H) {
  constexpr int NT = KD/64;        // 12
  constexpr int NITER = NT/2;      // 6
  __shared__ unsigned short lds[81920];

  const int bid = blockIdx.x;
  const int chunk = gridDim.x >> 3;
  const int tile = (bid & 7)*chunk + (bid >> 3);
  const int e = tile / 120;
  const int rem = tile % 120;
  const int nt = rem / 5, mt = rem % 5;

  const int tid = threadIdx.x;
  const int l = tid & 63, wid = tid >> 6;
  const int wr = wid >> 2, wc = wid & 3;
  const int lrow = l & 15, khi = l >> 4;

  const unsigned short* Ab = A  + (size_t)e*CAP*KD      + (size_t)mt*256*KD;
  const unsigned short* Bb = Bw + (size_t)e*(2*IDIM)*KD + (size_t)nt*256*KD;

  const int srow = tid >> 3;
  const int scol = (tid & 7) ^ (srow & 7);
  const size_t lane_off = (size_t)srow*KD + scol*8;
  const int lds_st = wid*512;

#define STG(dstu, srcp, half, kt) do { \
    const unsigned short* s_ = (srcp) + lane_off + (size_t)(half)*128*KD + (size_t)(kt)*64; \
    unsigned short* d_ = (unsigned short*)lds + (dstu) + (half)*8192 + lds_st; \
    __builtin_amdgcn_global_load_lds((const __attribute__((address_space(1))) void*)s_, \
        (__attribute__((address_space(3))) void*)d_, 16, 0, 0); \
    __builtin_amdgcn_global_load_lds((const __attribute__((address_space(1))) void*)(s_ + (size_t)64*KD), \
        (__attribute__((address_space(3))) void*)(d_ + 4096), 16, 0, 0); \
  } while(0)

  const int swz0 = ((khi    ) ^ (lrow & 7)) * 8;
  const int swz1 = ((4 + khi) ^ (lrow & 7)) * 8;
  const int aoff = wr*8192 + lrow*64;
  const int boff = (wc>>1)*8192 + ((wc&1)*64 + lrow)*64;

#define LDA(ab, dst, mb) do { _Pragma("unroll") for (int m_=0;m_<4;++m_) { \
    dst[m_][0] = *(const short8*)(lds + (ab) + aoff + ((mb)+m_)*1024 + swz0); \
    dst[m_][1] = *(const short8*)(lds + (ab) + aoff + ((mb)+m_)*1024 + swz1); } } while(0)
#define LDB(bb, dst, nb) do { _Pragma("unroll") for (int n_=0;n_<2;++n_) { \
    dst[n_][0] = *(const short8*)(lds + (bb) + boff + ((nb)+n_)*1024 + swz0); \
    dst[n_][1] = *(const short8*)(lds + (bb) + boff + ((nb)+n_)*1024 + swz1); } } while(0)
#define QUAD(af, bf, mb, nb) do { _Pragma("unroll") for (int r_=0;r_<2;++r_) \
    _Pragma("unroll") for (int n_=0;n_<2;++n_) \
    _Pragma("unroll") for (int m_=0;m_<4;++m_) \
      acc[(mb)+m_][(nb)+n_] = __builtin_amdgcn_mfma_f32_16x16x32_bf16(af[m_][r_], bf[n_][r_], acc[(mb)+m_][(nb)+n_], 0,0,0); } while(0)

  f32x4 acc[8][4];
#pragma unroll
  for (int i = 0; i < 8; ++i)
#pragma unroll
    for (int j = 0; j < 4; ++j) acc[i][j] = (f32x4){0.f,0.f,0.f,0.f};

  short8 a[4][2], bl[2][2], bh[2][2];

  int bA_ = 32768, bB_ = 49152, bC_ = 65536;

  STG(0, Ab, 0, 0);      STG(bA_, Bb, 0, 0);
  STG(0, Ab, 1, 0);      STG(bA_, Bb, 1, 0);
  STG(16384, Ab, 0, 1);  STG(bB_, Bb, 0, 1);
  STG(16384, Ab, 1, 1);  STG(bB_, Bb, 1, 1);
  VMW(8);
  BAR;

#define ITER(t2, t3, DOS, VM4, VM8) \
    LDA(0, a, 0); LDB(bA_, bl, 0); if (DOS) STG(bC_, Bb, 0, (t2)); \
    BAR; P1; QUAD(a, bl, 0, 0); P0; BAR; \
    LDB(bA_, bh, 2); if (DOS) STG(bC_, Bb, 1, (t2)); \
    BAR; P1; QUAD(a, bh, 0, 2); P0; BAR; \
    LDA(0, a, 4); \
    BAR; P1; QUAD(a, bh, 4, 2); P0; BAR; \
    if (DOS) STG(0, Ab, 0, (t2)); VM4; \
    BAR; P1; QUAD(a, bl, 4, 0); P0; BAR; \
    LDA(16384, a, 0); LDB(bB_, bl, 0); if (DOS) { STG(0, Ab, 1, (t2)); STG(bA_, Bb, 0, (t3)); } \
    BAR; P1; QUAD(a, bl, 0, 0); P0; BAR; \
    LDB(bB_, bh, 2); if (DOS) STG(bA_, Bb, 1, (t3)); \
    BAR; P1; QUAD(a, bh, 0, 2); P0; BAR; \
    LDA(16384, a, 4); \
    BAR; P1; QUAD(a, bh, 4, 2); P0; BAR; \
    if (DOS) { STG(16384, Ab, 0, (t3)); STG(16384, Ab, 1, (t3)); } VM8; \
    BAR; P1; QUAD(a, bl, 4, 0); P0; BAR;

#pragma unroll 1
  for (int i = 0; i < NITER-1; ++i) {
    const int t2 = 2*i+2, t3 = 2*i+3;
    ITER(t2, t3, true, VMW(6), VMW(8));
    int tmp = bC_; bC_ = bB_; bB_ = bA_; bA_ = tmp;
  }
  ITER(0, 0, false, VMW(0), VMW(0));

#undef ITER

  __syncthreads();
  {
    const int cb0 = wc*32 + lrow;
    const int rb0 = wr*128 + khi*4;
#pragma unroll
    for (int m = 0; m < 8; ++m)
#pragma unroll
      for (int p = 0; p < 2; ++p) {
        f32x4 g = acc[m][2*p], u = acc[m][2*p+1];
#pragma unroll
        for (int r = 0; r < 4; ++r) {
          float gv = g[r];
          float hv = gv / (1.f + __expf(-gv)) * u[r];
          lds[(rb0 + m*16 + r)*136 + cb0 + p*16] = f2b(hv);
        }
      }
  }
  __syncthreads();
  const size_t rowg = (size_t)e*CAP + (size_t)mt*256;
  const size_t colg = (size_t)nt*128 + (size_t)(l & 15)*8;
#pragma unroll
  for (int i = 0; i < 8; ++i) {
    int row = wid*32 + i*4 + (l >> 4);
    us8 v = *(const us8*)(lds + row*136 + (l & 15)*8);
    *(us8*)(H + (rowg + row)*(size_t)IDIM + colg) = v;
  }
#undef QUAD
#undef LDB
#undef LDA
#undef STG
}

// =============== GEMM2: 256x128 8-phase deep pipeline (K=3072, 24 ITERs) =====
// A = h [E][CAP][KD], B = WpT [E][CDIM][KD], out bf16 [E][CAP][CDIM].
// 8 waves as 4(M) x 2(N); per wave 64x64 out = acc[4][4].
// LDS 112 KiB: A0@0, A1@16384, B@{32768,40960,49152} (ushort units).
// Same verified sync discipline as gemm1: VMW before the BAR guarding
// cross-wave reads; counted VMW(6) steady-state; 6 loads/tile (4A+2B).
template<int KD>
__global__ __launch_bounds__(512, 2) void gemm2_8ph(
    const unsigned short* __restrict__ A,
    const unsigned short* __restrict__ Bw,
    unsigned short* __restrict__ O) {
  constexpr int NT = KD/64;        // 48
  constexpr int NITER = NT/2;      // 24
  __shared__ unsigned short lds[57344];

  const int bid = blockIdx.x;
  const int chunk = gridDim.x >> 3;              // 30 = one expert per XCD
  const int tile = (bid & 7)*chunk + (bid >> 3);
  const int e = tile / 30;
  const int rem = tile % 30;
  const int nt = rem / 5, mt = rem % 5;          // 6 nt x 5 mt

  const int tid = threadIdx.x;
  const int l = tid & 63, wid = tid >> 6;
  const int wr = wid >> 1, wc = wid & 1;
  const int lrow = l & 15, khi = l >> 4;

  const unsigned short* Ab = A  + (size_t)e*CAP*KD  + (size_t)mt*256*KD;
  const unsigned short* Bb = Bw + (size_t)e*CDIM*KD + (size_t)nt*128*KD;

  const int srow = tid >> 3;
  const int scol = (tid & 7) ^ (srow & 7);
  const size_t lane_off = (size_t)srow*KD + scol*8;
  const int lds_st = wid*512;

  // STG stages 128 rows (2 global_load_lds); A tile = 2 calls (half 0/1),
  // B tile (128 rows) = 1 call (half 0).
#define STG(dstu, srcp, half, kt) do { \
    const unsigned short* s_ = (srcp) + lane_off + (size_t)(half)*128*KD + (size_t)(kt)*64; \
    unsigned short* d_ = (unsigned short*)lds + (dstu) + (half)*8192 + lds_st; \
    __builtin_amdgcn_global_load_lds((const __attribute__((address_space(1))) void*)s_, \
        (__attribute__((address_space(3))) void*)d_, 16, 0, 0); \
    __builtin_amdgcn_global_load_lds((const __attribute__((address_space(1))) void*)(s_ + (size_t)64*KD), \
        (__attribute__((address_space(3))) void*)(d_ + 4096), 16, 0, 0); \
  } while(0)

  const int swz0 = ((khi    ) ^ (lrow & 7)) * 8;
  const int swz1 = ((4 + khi) ^ (lrow & 7)) * 8;
  const int aoff = wr*4096 + lrow*64;            // rows: wr*64 + m*16 + lrow
  const int boff = wc*4096 + lrow*64;            // rows: wc*64 + n*16 + lrow

#define LDA(ab, dst) do { _Pragma("unroll") for (int m_=0;m_<4;++m_) { \
    dst[m_][0] = *(const short8*)(lds + (ab) + aoff + m_*1024 + swz0); \
    dst[m_][1] = *(const short8*)(lds + (ab) + aoff + m_*1024 + swz1); } } while(0)
#define LDB(bb, dst, nb) do { _Pragma("unroll") for (int n_=0;n_<2;++n_) { \
    dst[n_][0] = *(const short8*)(lds + (bb) + boff + ((nb)+n_)*1024 + swz0); \
    dst[n_][1] = *(const short8*)(lds + (bb) + boff + ((nb)+n_)*1024 + swz1); } } while(0)
#define QUAD(af, bf, nb) do { _Pragma("unroll") for (int r_=0;r_<2;++r_) \
    _Pragma("unroll") for (int n_=0;n_<2;++n_) \
    _Pragma("unroll") for (int m_=0;m_<4;++m_) \
      acc[m_][(nb)+n_] = __builtin_amdgcn_mfma_f32_16x16x32_bf16(af[m_][r_], bf[n_][r_], acc[m_][(nb)+n_], 0,0,0); } while(0)

  f32x4 acc[4][4];
#pragma unroll
  for (int i = 0; i < 4; ++i)
#pragma unroll
    for (int j = 0; j < 4; ++j) acc[i][j] = (f32x4){0.f,0.f,0.f,0.f};

  short8 a[4][2], bl[2][2], bh[2][2];

  int bA_ = 32768, bB_ = 40960, bC_ = 49152;

  // prologue: tile0's 6 loads first, then tile1's 6; VMW(6) retires tile0.
  STG(0, Ab, 0, 0); STG(0, Ab, 1, 0); STG(bA_, Bb, 0, 0);
  STG(16384, Ab, 0, 1); STG(16384, Ab, 1, 1); STG(bB_, Bb, 0, 1);
  VMW(6);
  BAR;

  // ITER (t even in A0/bA_, t+1 in A1/bB_); 4 phases:
  //  ph1: read t frags (A0 all, bA_ lo) | stage B(t+2)->bC_ (2)
  //  ph2: read bA_ hi | stage A(t+2)->A0 (4) | VMW(6): retires t+1
  //  ph3: read t+1 frags (A1 all, bB_ lo) | stage B(t+3)->bA_ (2)
  //  ph4: read bB_ hi | stage A(t+3)->A1 (4) | VMW(6): retires t+2
#define ITER2(t2, t3, DOS, VM2, VM4) \
    LDA(0, a); LDB(bA_, bl, 0); if (DOS) STG(bC_, Bb, 0, (t2)); \
    BAR; P1; QUAD(a, bl, 0); P0; BAR; \
    LDB(bA_, bh, 2); if (DOS) { STG(0, Ab, 0, (t2)); STG(0, Ab, 1, (t2)); } VM2; \
    BAR; P1; QUAD(a, bh, 2); P0; BAR; \
    LDA(16384, a); LDB(bB_, bl, 0); if (DOS) STG(bA_, Bb, 0, (t3)); \
    BAR; P1; QUAD(a, bl, 0); P0; BAR; \
    LDB(bB_, bh, 2); if (DOS) { STG(16384, Ab, 0, (t3)); STG(16384, Ab, 1, (t3)); } VM4; \
    BAR; P1; QUAD(a, bh, 2); P0; BAR;

#pragma unroll 1
  for (int i = 0; i < NITER-1; ++i) {
    const int t2 = 2*i+2, t3 = 2*i+3;
    ITER2(t2, t3, true, VMW(6), VMW(6));
    int tmp = bC_; bC_ = bB_; bB_ = bA_; bA_ = tmp;
  }
  ITER2(0, 0, false, VMW(0), VMW(0));

#undef ITER2
#undef QUAD
#undef LDB
#undef LDA
#undef STG

  // epilogue: f32->bf16 via LDS (stride 136), coalesced us8 stores
  __syncthreads();
  {
    const int cb0 = wc*64 + lrow;
    const int rb0 = wr*64 + khi*4;
#pragma unroll
    for (int m = 0; m < 4; ++m)
#pragma unroll
      for (int n = 0; n < 4; ++n) {
        f32x4 v = acc[m][n];
#pragma unroll
        for (int r = 0; r < 4; ++r)
          lds[(rb0 + m*16 + r)*136 + cb0 + n*16] = f2b(v[r]);
      }
  }
  __syncthreads();
  const size_t rowg = (size_t)e*CAP + (size_t)mt*256;
  const size_t colg = (size_t)nt*128 + (size_t)(l & 15)*8;
#pragma unroll
  for (int i = 0; i < 8; ++i) {
    int row = wid*32 + i*4 + (l >> 4);
    us8 v = *(const us8*)(lds + row*136 + (l & 15)*8);
    *(us8*)(O + (rowg + row)*(size_t)CDIM + colg) = v;
  }
}

// ---------------- combine (bf16 expert outputs -> f32 y) ----------------
__global__ __launch_bounds__(192) void combine_kernel(const unsigned short* __restrict__ outbuf,
    const int* __restrict__ c1, const int* __restrict__ c2,
    const float* __restrict__ g1, const float* __restrict__ g2,
    float* __restrict__ y) {
  int t = blockIdx.x;
  int q = threadIdx.x;
  float f1 = g1[t], f2 = g2[t];
  int a = c1[t], b = c2[t];
  us4 va = ((const us4*)outbuf)[(size_t)a*(CDIM/4) + q];
  us4 vb = ((const us4*)outbuf)[(size_t)b*(CDIM/4) + q];
  float4 r;
  r.x = f1*b2f(va.x) + f2*b2f(vb.x);
  r.y = f1*b2f(va.y) + f2*b2f(vb.y);
  r.z = f1*b2f(va.z) + f2*b2f(vb.z);
  r.w = f1*b2f(va.w) + f2*b2f(vb.w);
  ((float4*)y)[(size_t)t*(CDIM/4) + q] = r;
}

extern "C" void kernel_launch(void* const* d_in, const int* in_sizes, int n_in,
                              void* d_out, int out_size, void* d_ws, size_t ws_size,
                              hipStream_t stream) {
  const float* x  = (const float*)d_in[0];
  const float* Wr = (const float*)d_in[1];
  const float* Wg = (const float*)d_in[2];
  const float* Wu = (const float*)d_in[3];
  const float* Wp = (const float*)d_in[4];
  float* y = (float*)d_out;

  char* p = (char*)d_ws;
  auto alloc = [&](size_t bytes) { char* r = p; p += (bytes + 255) & ~(size_t)255; return r; };
  unsigned short* WguT = (unsigned short*)alloc((size_t)NEXP*2*IDIM*CDIM*2);
  unsigned short* WpT  = (unsigned short*)alloc((size_t)NEXP*CDIM*IDIM*2);
  unsigned short* ein  = (unsigned short*)alloc((size_t)EROWS*CDIM*2);
  unsigned short* h    = (unsigned short*)alloc((size_t)EROWS*IDIM*2);
  unsigned short* outbuf = (unsigned short*)alloc((size_t)EROWS*CDIM*2);
  float* probs  = (float*)alloc((size_t)NTOK*NEXP*4);
  int* idx1 = (int*)alloc(NTOK*4);
  int* idx2 = (int*)alloc(NTOK*4);
  int* c1   = (int*)alloc(NTOK*4);
  int* c2   = (int*)alloc(NTOK*4);
  float* g1r = (float*)alloc(NTOK*4);
  float* g2r = (float*)alloc(NTOK*4);
  float* g1o = (float*)alloc(NTOK*4);
  float* g2o = (float*)alloc(NTOK*4);
  int* bufmap = (int*)alloc(EROWS*4);

  size_t required = (size_t)(p - (char*)d_ws);
  if (ws_size < required) return;

  hipMemsetAsync(bufmap, 0xFF, EROWS*sizeof(int), stream);

  wgu_cvt64<<<2*NEXP*(CDIM/64)*(IDIM/64), 256, 0, stream>>>(Wg, Wu, WguT);
  transpose_cvt64<<<NEXP*(IDIM/64)*(CDIM/64), 256, 0, stream>>>(Wp, WpT, IDIM, CDIM);

  router_kernel<<<NTOK/4, 256, 0, stream>>>(x, Wr, probs, idx1, idx2, g1r, g2r);
  scan_kernel<<<1, 1024, 0, stream>>>(idx1, idx2, g1r, g2r, probs, bufmap,
                                      c1, c2, g1o, g2o, y + (size_t)NTOK*CDIM);
  dispatch_kernel<<<EROWS, 192, 0, stream>>>(x, bufmap, ein);

  gemm1_8ph<CDIM><<<NEXP*5*(2*IDIM/256), 512, 0, stream>>>(ein, WguT, h);
  gemm2_8ph<IDIM><<<NEXP*5*(CDIM/128), 512, 0, stream>>>(h, WpT, outbuf);

  combine_kernel<<<NTOK, 192, 0, stream>>>(outbuf, c1, c2, g1o, g2o, y);
}